// Round 17
// baseline (185.952 us; speedup 1.0000x reference)
//
#include <hip/hip_runtime.h>
#include <hip/hip_bf16.h>
#include <stdint.h>
#include <stddef.h>

// MultiHA: y@Wq^T -> q; x@Wk^T -> k; x@Wv^T -> v; causal softmax attn; @Wp^T + bp
// B=4 S=2048 D=1024 NH=16 HS=64. All GEMM/attn compute in bf16 MFMA, f32 accum.

typedef __attribute__((ext_vector_type(4))) float f32x4;
typedef __attribute__((ext_vector_type(8))) short s16x8;
typedef __attribute__((ext_vector_type(4))) float float4v;
typedef __attribute__((ext_vector_type(4))) int i32x4;
typedef __attribute__((ext_vector_type(2))) unsigned int u32x2;

#define DEV __device__ __forceinline__

constexpr int Bsz = 4, Sseq = 2048, Dm = 1024, NHn = 16, HSn = 64;
// fold 1/sqrt(HS) * log2(e) into Wq so attention softmax runs in exp2 domain
constexpr float QSCALE = 0.125f * 1.4426950408889634f;

// ---- workspace layout (bytes) ----
constexpr size_t SZ_BF_XY = (size_t)Bsz * Sseq * Dm * 2;  // 16 MiB
constexpr size_t SZ_W     = (size_t)Dm * Dm * 2;          // 2 MiB
constexpr size_t OFF_XBF  = 0;
constexpr size_t OFF_YBF  = OFF_XBF + SZ_BF_XY;
constexpr size_t OFF_WQ   = OFF_YBF + SZ_BF_XY;
constexpr size_t OFF_WK   = OFF_WQ + SZ_W;
constexpr size_t OFF_WV   = OFF_WK + SZ_W;
constexpr size_t OFF_WP   = OFF_WV + SZ_W;
constexpr size_t OFF_QWS  = OFF_WP + SZ_W;   // [BH][S][64] bf16
constexpr size_t OFF_KWS  = OFF_QWS + SZ_BF_XY;
constexpr size_t OFF_VTWS = OFF_KWS + SZ_BF_XY; // [BH][64][S] bf16 (V transposed)
constexpr size_t OFF_OWS  = OFF_VTWS + SZ_BF_XY; // attn out [B][S][D] bf16
constexpr size_t OFF_FLAG = OFF_OWS + SZ_BF_XY;

DEV unsigned short f2bf(float f) {
  union { float f; unsigned int u; } v; v.f = f;
  unsigned int r = (v.u + 0x7FFFu + ((v.u >> 16) & 1u)) >> 16;
  return (unsigned short)r;
}

DEV void gll16(const void* g, void* l) {
  __builtin_amdgcn_global_load_lds((const __attribute__((address_space(1))) unsigned int*)g,
                                   (__attribute__((address_space(3))) unsigned int*)l, 16, 0, 0);
}

DEV unsigned int cvtpk(float a, float b) {
  unsigned int r;
  asm("v_cvt_pk_bf16_f32 %0, %1, %2" : "=v"(r) : "v"(a), "v"(b));
  return r;
}

union U8 { s16x8 v; unsigned int u[4]; };

// ------ fused fp32->bf16 conversion of all inputs + pad/tmask triviality check ------
__global__ void cvt_all(const float* __restrict__ x, const float* __restrict__ y,
                        const float* __restrict__ Wq, const float* __restrict__ Wk,
                        const float* __restrict__ Wv, const float* __restrict__ Wp,
                        const int* __restrict__ pad, const int* __restrict__ tmask,
                        char* __restrict__ ws, int* __restrict__ flags) {
  const int blk = blockIdx.x;
  if (blk >= 10240) {
    int bad = 0;
    if (blk < 10248) { // pad: 8192 ints, 4 per thread
      const i32x4 v = ((const i32x4*)pad)[(blk - 10240) * 256 + threadIdx.x];
      bad = (v[0] == 0) | (v[1] == 0) | (v[2] == 0) | (v[3] == 0);
    } else { // tmask: 4M ints, 8 per thread
      const i32x4* tp = (const i32x4*)tmask + ((size_t)(blk - 10248) * 256 + threadIdx.x) * 2;
      i32x4 v0 = tp[0], v1 = tp[1];
      bad = (v0[0] == 0) | (v0[1] == 0) | (v0[2] == 0) | (v0[3] == 0) |
            (v1[0] == 0) | (v1[1] == 0) | (v1[2] == 0) | (v1[3] == 0);
    }
    if (__builtin_amdgcn_ballot_w64(bad) != 0 && (threadIdx.x & 63) == 0)
      atomicOr(flags, 1);
    return;
  }
  const float* src;
  unsigned short* dst;
  int b8;
  float scale = 1.f;
  if (blk < 4096)      { src = x;  dst = (unsigned short*)(ws + OFF_XBF); b8 = blk; }
  else if (blk < 8192) { src = y;  dst = (unsigned short*)(ws + OFF_YBF); b8 = blk - 4096; }
  else if (blk < 8704) { src = Wq; dst = (unsigned short*)(ws + OFF_WQ);  b8 = blk - 8192; scale = QSCALE; }
  else if (blk < 9216) { src = Wk; dst = (unsigned short*)(ws + OFF_WK);  b8 = blk - 8704; }
  else if (blk < 9728) { src = Wv; dst = (unsigned short*)(ws + OFF_WV);  b8 = blk - 9216; }
  else                 { src = Wp; dst = (unsigned short*)(ws + OFF_WP);  b8 = blk - 9728; }
  const size_t i = (size_t)b8 * 256 + threadIdx.x;
  const float4v* s = (const float4v*)src + i * 2;
  float4v a = s[0], b = s[1];
  s16x8 o;
  o[0] = (short)f2bf(a[0] * scale); o[1] = (short)f2bf(a[1] * scale);
  o[2] = (short)f2bf(a[2] * scale); o[3] = (short)f2bf(a[3] * scale);
  o[4] = (short)f2bf(b[0] * scale); o[5] = (short)f2bf(b[1] * scale);
  o[6] = (short)f2bf(b[2] * scale); o[7] = (short)f2bf(b[3] * scale);
  *(s16x8*)(dst + i * 8) = o;
}

// ---------------- Q projection GEMM (2-phase double-buffered staging) ----------------
__global__ __launch_bounds__(256) void q_gemm(const unsigned short* __restrict__ A,
                                              const unsigned short* __restrict__ W,
                                              unsigned short* __restrict__ outb) {
  constexpr int K = 1024;
  __shared__ unsigned short sm[2][8192]; // [buf][lA 4096 | lB 4096]
  const int tid = threadIdx.x;
  const int w = tid >> 6, lane = tid & 63, lo = lane & 15, hi = lane >> 4;
  const int wm = w >> 1, wn = w & 1;
  const int m0 = blockIdx.x * 128, n0 = blockIdx.y * 128;
  f32x4 acc[4][4] = {};

  auto stage = [&](int buf, int k0) {
#pragma unroll
    for (int h = 0; h < 2; ++h) {
      int c = w * 64 + h * 256 + lane;
      gll16(A + (size_t)(m0 + (c >> 2)) * K + k0 + (c & 3) * 8, &sm[buf][0] + (size_t)(w * 64 + h * 256) * 8);
      gll16(W + (size_t)(n0 + (c >> 2)) * K + k0 + (c & 3) * 8, &sm[buf][4096] + (size_t)(w * 64 + h * 256) * 8);
    }
  };

  stage(0, 0);
  __syncthreads(); // drains vmcnt -> buf0 ready
  for (int t = 0; t < 32; ++t) {
    if (t < 31) stage((t + 1) & 1, (t + 1) * 32); // issue next tile early
    const unsigned short* lA = &sm[t & 1][0];
    const unsigned short* lB = &sm[t & 1][4096];
    s16x8 af[4], bfr[4];
#pragma unroll
    for (int mi = 0; mi < 4; ++mi) af[mi] = *(const s16x8*)&lA[(wm * 64 + mi * 16 + lo) * 32 + hi * 8];
#pragma unroll
    for (int ni = 0; ni < 4; ++ni) bfr[ni] = *(const s16x8*)&lB[(wn * 64 + ni * 16 + lo) * 32 + hi * 8];
#pragma unroll
    for (int mi = 0; mi < 4; ++mi)
#pragma unroll
      for (int ni = 0; ni < 4; ++ni)
        acc[mi][ni] = __builtin_amdgcn_mfma_f32_16x16x32_bf16(af[mi], bfr[ni], acc[mi][ni], 0, 0, 0);
    __syncthreads(); // readers done + next-tile loads drained
  }
#pragma unroll
  for (int mi = 0; mi < 4; ++mi)
#pragma unroll
    for (int ni = 0; ni < 4; ++ni)
#pragma unroll
      for (int j = 0; j < 4; ++j) {
        int m = m0 + wm * 64 + mi * 16 + hi * 4 + j;
        int n = n0 + wn * 64 + ni * 16 + lo;
        int b = m >> 11, s = m & 2047, hh = n >> 6, e = n & 63;
        outb[((size_t)(b * NHn + hh) * Sseq + s) * HSn + e] = f2bf(acc[mi][ni][j]);
      }
}

// -------- merged K+V projection GEMM (shared x staging, 2-phase double-buffer) --------
__global__ __launch_bounds__(256, 2) void kv_gemm(const unsigned short* __restrict__ A,
                                                  const unsigned short* __restrict__ Wk,
                                                  const unsigned short* __restrict__ Wv,
                                                  unsigned short* __restrict__ kws,
                                                  unsigned short* __restrict__ vtw) {
  constexpr int K = 1024;
  __shared__ unsigned short sm[2][12288]; // [buf][lA | lBk | lBv]; epilogue reuses flat
  const int tid = threadIdx.x;
  const int w = tid >> 6, lane = tid & 63, lo = lane & 15, hi = lane >> 4;
  const int wm = w >> 1, wn = w & 1;
  const int m0 = blockIdx.x * 128, n0 = blockIdx.y * 128;
  f32x4 acck[4][4] = {}, accv[4][4] = {};

  auto stage = [&](int buf, int k0) {
#pragma unroll
    for (int h = 0; h < 2; ++h) {
      int c = w * 64 + h * 256 + lane;
      size_t roff = (size_t)(c >> 2) * K + k0 + (c & 3) * 8;
      size_t loff = (size_t)(w * 64 + h * 256) * 8;
      gll16(A + (size_t)m0 * K + roff, &sm[buf][0] + loff);
      gll16(Wk + (size_t)n0 * K + roff, &sm[buf][4096] + loff);
      gll16(Wv + (size_t)n0 * K + roff, &sm[buf][8192] + loff);
    }
  };

  stage(0, 0);
  __syncthreads();
  for (int t = 0; t < 32; ++t) {
    if (t < 31) stage((t + 1) & 1, (t + 1) * 32);
    const unsigned short* lA = &sm[t & 1][0];
    const unsigned short* lBk = &sm[t & 1][4096];
    const unsigned short* lBv = &sm[t & 1][8192];
    s16x8 af[4], bfk[4], bfv[4];
#pragma unroll
    for (int mi = 0; mi < 4; ++mi) af[mi] = *(const s16x8*)&lA[(wm * 64 + mi * 16 + lo) * 32 + hi * 8];
#pragma unroll
    for (int ni = 0; ni < 4; ++ni) {
      bfk[ni] = *(const s16x8*)&lBk[(wn * 64 + ni * 16 + lo) * 32 + hi * 8];
      bfv[ni] = *(const s16x8*)&lBv[(wn * 64 + ni * 16 + lo) * 32 + hi * 8];
    }
#pragma unroll
    for (int mi = 0; mi < 4; ++mi)
#pragma unroll
      for (int ni = 0; ni < 4; ++ni) {
        acck[mi][ni] = __builtin_amdgcn_mfma_f32_16x16x32_bf16(af[mi], bfk[ni], acck[mi][ni], 0, 0, 0);
        accv[mi][ni] = __builtin_amdgcn_mfma_f32_16x16x32_bf16(af[mi], bfv[ni], accv[mi][ni], 0, 0, 0);
      }
    __syncthreads();
  }

  // K epilogue: direct global stores
#pragma unroll
  for (int mi = 0; mi < 4; ++mi)
#pragma unroll
    for (int ni = 0; ni < 4; ++ni)
#pragma unroll
      for (int j = 0; j < 4; ++j) {
        int m = m0 + wm * 64 + mi * 16 + hi * 4 + j;
        int n = n0 + wn * 64 + ni * 16 + lo;
        int b = m >> 11, s = m & 2047, hh = n >> 6, e = n & 63;
        kws[((size_t)(b * NHn + hh) * Sseq + s) * HSn + e] = f2bf(acck[mi][ni][j]);
      }
  // V epilogue: LDS transpose (reuses sm flat: needs 17408 shorts < 24576)
  unsigned short* tp = &sm[0][0];
  __syncthreads();
#pragma unroll
  for (int mi = 0; mi < 4; ++mi)
#pragma unroll
    for (int ni = 0; ni < 4; ++ni)
#pragma unroll
      for (int j = 0; j < 4; ++j) {
        int ml = wm * 64 + mi * 16 + hi * 4 + j;
        int nl = wn * 64 + ni * 16 + lo;
        tp[(size_t)nl * 136 + ml] = f2bf(accv[mi][ni][j]);
      }
  __syncthreads();
  int nl = tid >> 1, half = tid & 1;
  int b = m0 >> 11, hh = (n0 + nl) >> 6, e = (n0 + nl) & 63;
  unsigned short* dst = vtw + ((size_t)(b * NHn + hh) * HSn + e) * Sseq + (m0 & 2047) + half * 64;
#pragma unroll
  for (int i = 0; i < 8; ++i)
    *(s16x8*)(dst + i * 8) = *(const s16x8*)&tp[(size_t)nl * 136 + half * 64 + i * 8];
}

// ---------------- final projection GEMM (2-phase): fp32 out [M][1024] + bias ----------
__global__ __launch_bounds__(256) void gemm_p(const unsigned short* __restrict__ A,
                                              const unsigned short* __restrict__ W,
                                              float* __restrict__ outf,
                                              const float* __restrict__ bias) {
  constexpr int K = 1024;
  __shared__ unsigned short sm[2][8192];
  const int tid = threadIdx.x;
  const int w = tid >> 6, lane = tid & 63, lo = lane & 15, hi = lane >> 4;
  const int wm = w >> 1, wn = w & 1;
  const int m0 = blockIdx.x * 128, n0 = blockIdx.y * 128;
  f32x4 acc[4][4] = {};

  auto stage = [&](int buf, int k0) {
#pragma unroll
    for (int h = 0; h < 2; ++h) {
      int c = w * 64 + h * 256 + lane;
      gll16(A + (size_t)(m0 + (c >> 2)) * K + k0 + (c & 3) * 8, &sm[buf][0] + (size_t)(w * 64 + h * 256) * 8);
      gll16(W + (size_t)(n0 + (c >> 2)) * K + k0 + (c & 3) * 8, &sm[buf][4096] + (size_t)(w * 64 + h * 256) * 8);
    }
  };

  stage(0, 0);
  __syncthreads();
  for (int t = 0; t < 32; ++t) {
    if (t < 31) stage((t + 1) & 1, (t + 1) * 32);
    const unsigned short* lA = &sm[t & 1][0];
    const unsigned short* lB = &sm[t & 1][4096];
    s16x8 af[4], bfr[4];
#pragma unroll
    for (int mi = 0; mi < 4; ++mi) af[mi] = *(const s16x8*)&lA[(wm * 64 + mi * 16 + lo) * 32 + hi * 8];
#pragma unroll
    for (int ni = 0; ni < 4; ++ni) bfr[ni] = *(const s16x8*)&lB[(wn * 64 + ni * 16 + lo) * 32 + hi * 8];
#pragma unroll
    for (int mi = 0; mi < 4; ++mi)
#pragma unroll
      for (int ni = 0; ni < 4; ++ni)
        acc[mi][ni] = __builtin_amdgcn_mfma_f32_16x16x32_bf16(af[mi], bfr[ni], acc[mi][ni], 0, 0, 0);
    __syncthreads();
  }
  float bv[4];
#pragma unroll
  for (int ni = 0; ni < 4; ++ni) bv[ni] = bias[n0 + wn * 64 + ni * 16 + lo];
#pragma unroll
  for (int mi = 0; mi < 4; ++mi)
#pragma unroll
    for (int ni = 0; ni < 4; ++ni)
#pragma unroll
      for (int j = 0; j < 4; ++j) {
        int m = m0 + wm * 64 + mi * 16 + hi * 4 + j;
        int n = n0 + wn * 64 + ni * 16 + lo;
        outf[(size_t)m * 1024 + n] = acc[mi][ni][j] + bv[ni];
      }
}

// ---------------- flash attention (4-wave, 32 rows/wave, permuted-K, in-reg P) --------
// R17: R5's verified 32-row/wave geometry (each kfr/vfr LDS read feeds the 2 mq
// subtiles of the SAME q-tile, unconditionally - no cross-tile conditionals) combined
// with R13's verified math (permuted-K zero-LDS P, defer-max thr=11, l via ones-MFMA).
// Grid (64,8), 256 threads = 4 waves; wave w owns rows qt*128 + w*32 .. +31.
// K rows staged bit-permuted: storage row s holds logical ((s&0x1C)<<1)|((s&0x20)>>3)|(s&3);
// QK^T slot (mq,t,hi,j) = S[kpos = k0+32(t&1)+8hi+4(t>>1)+j][q = qw0+mq*16+lo];
// PV B-fragment per mq is a pure register rearrangement of packed P.
DEV void attn_unit32(const unsigned short* __restrict__ kbc,
                     const unsigned short* __restrict__ vbc,
                     const s16x8 (&qf)[2][2], f32x4 (&oacc)[4][2], f32x4 (&lacc)[2],
                     float (&mrun)[2], const s16x8& ones,
                     int k0, int qw0, int lo, int hi, int b,
                     const int* __restrict__ pad, const int* __restrict__ tmask,
                     bool trivial) {
  if (k0 > qw0 + 31) return; // wave-uniform: tile entirely above this wave's rows

  // S^T = K Q^T for both mq subtiles; each kfr read feeds 2 MFMAs
  f32x4 st[2][4];
  __builtin_amdgcn_s_setprio(1);
#pragma unroll
  for (int t = 0; t < 4; ++t) {
    const s16x8 kf0 = *(const s16x8*)&kbc[(t * 16 + lo) * 72 + hi * 8];
    const s16x8 kf1 = *(const s16x8*)&kbc[(t * 16 + lo) * 72 + 32 + hi * 8];
    f32x4 z0 = {0.f, 0.f, 0.f, 0.f}, z1 = {0.f, 0.f, 0.f, 0.f};
    z0 = __builtin_amdgcn_mfma_f32_16x16x32_bf16(kf0, qf[0][0], z0, 0, 0, 0);
    z0 = __builtin_amdgcn_mfma_f32_16x16x32_bf16(kf1, qf[0][1], z0, 0, 0, 0);
    z1 = __builtin_amdgcn_mfma_f32_16x16x32_bf16(kf0, qf[1][0], z1, 0, 0, 0);
    z1 = __builtin_amdgcn_mfma_f32_16x16x32_bf16(kf1, qf[1][1], z1, 0, 0, 0);
    st[0][t] = z0; st[1][t] = z1;
  }
  __builtin_amdgcn_s_setprio(0);

  const int kgb = k0 + hi * 8; // logical kpos base for this lane's slots
  U8 pf[2][2];
#pragma unroll
  for (int mq = 0; mq < 2; ++mq) {
    const int qg = qw0 + mq * 16 + lo;
    if (k0 + 63 > qw0) { // boundary tiles: causal mask (logical kpos > q)
#pragma unroll
      for (int t = 0; t < 4; ++t)
#pragma unroll
        for (int j = 0; j < 4; ++j) {
          int kg = kgb + ((t & 1) << 5) + ((t >> 1) << 2) + j;
          if (kg > qg) st[mq][t][j] = -3e38f;
        }
    }
    if (!trivial) { // general pad/time masks (not hit for all-ones inputs)
#pragma unroll
      for (int t = 0; t < 4; ++t)
#pragma unroll
        for (int j = 0; j < 4; ++j) {
          int kg = kgb + ((t & 1) << 5) + ((t >> 1) << 2) + j;
          if (!pad[b * Sseq + kg] || !tmask[(size_t)qg * Sseq + kg]) st[mq][t][j] = -3e38f;
        }
    }
    // tile max (lane-local + 2 shuffles over hi-groups)
    float m0v = fmaxf(fmaxf(st[mq][0][0], st[mq][0][1]), fmaxf(st[mq][0][2], st[mq][0][3]));
    float m1v = fmaxf(fmaxf(st[mq][1][0], st[mq][1][1]), fmaxf(st[mq][1][2], st[mq][1][3]));
    float m2v = fmaxf(fmaxf(st[mq][2][0], st[mq][2][1]), fmaxf(st[mq][2][2], st[mq][2][3]));
    float m3v = fmaxf(fmaxf(st[mq][3][0], st[mq][3][1]), fmaxf(st[mq][3][2], st[mq][3][3]));
    float mx = fmaxf(fmaxf(m0v, m1v), fmaxf(m2v, m3v));
    mx = fmaxf(mx, __shfl_xor(mx, 16, 64));
    mx = fmaxf(mx, __shfl_xor(mx, 32, 64));
    // defer-max: only rescale when the bound would be exceeded (P <= 2^11 otherwise)
    if (!__all(mx <= mrun[mq] + 11.f)) {
      const float mnew = fmaxf(mrun[mq], mx);
      const float al = __builtin_amdgcn_exp2f(mrun[mq] - mnew);
      mrun[mq] = mnew;
#pragma unroll
      for (int et = 0; et < 4; ++et) oacc[et][mq] *= al;
      lacc[mq] *= al;
    }
    // P = exp2(S - mrun), packed to bf16 pairs in registers
    unsigned int pk[4][2];
#pragma unroll
    for (int t = 0; t < 4; ++t) {
      float p0 = __builtin_amdgcn_exp2f(st[mq][t][0] - mrun[mq]);
      float p1 = __builtin_amdgcn_exp2f(st[mq][t][1] - mrun[mq]);
      float p2 = __builtin_amdgcn_exp2f(st[mq][t][2] - mrun[mq]);
      float p3 = __builtin_amdgcn_exp2f(st[mq][t][3] - mrun[mq]);
      pk[t][0] = cvtpk(p0, p1);
      pk[t][1] = cvtpk(p2, p3);
    }
    // PV B-fragments (kpos = kk*32 + hi*8 + 0..7, col q = qw0+mq*16+lo)
    pf[mq][0].u[0] = pk[0][0]; pf[mq][0].u[1] = pk[0][1];
    pf[mq][0].u[2] = pk[2][0]; pf[mq][0].u[3] = pk[2][1];
    pf[mq][1].u[0] = pk[1][0]; pf[mq][1].u[1] = pk[1][1];
    pf[mq][1].u[2] = pk[3][0]; pf[mq][1].u[3] = pk[3][1];
  }

  // O^T += V^T P^T for both mq; each vfr read feeds 2 MFMAs. l += ones.P.
  __builtin_amdgcn_s_setprio(1);
#pragma unroll
  for (int et = 0; et < 4; ++et) {
    const s16x8 vf0 = *(const s16x8*)&vbc[(et * 16 + lo) * 72 + hi * 8];
    const s16x8 vf1 = *(const s16x8*)&vbc[(et * 16 + lo) * 72 + 32 + hi * 8];
    oacc[et][0] = __builtin_amdgcn_mfma_f32_16x16x32_bf16(vf0, pf[0][0].v, oacc[et][0], 0, 0, 0);
    oacc[et][0] = __builtin_amdgcn_mfma_f32_16x16x32_bf16(vf1, pf[0][1].v, oacc[et][0], 0, 0, 0);
    oacc[et][1] = __builtin_amdgcn_mfma_f32_16x16x32_bf16(vf0, pf[1][0].v, oacc[et][1], 0, 0, 0);
    oacc[et][1] = __builtin_amdgcn_mfma_f32_16x16x32_bf16(vf1, pf[1][1].v, oacc[et][1], 0, 0, 0);
  }
  lacc[0] = __builtin_amdgcn_mfma_f32_16x16x32_bf16(ones, pf[0][0].v, lacc[0], 0, 0, 0);
  lacc[0] = __builtin_amdgcn_mfma_f32_16x16x32_bf16(ones, pf[0][1].v, lacc[0], 0, 0, 0);
  lacc[1] = __builtin_amdgcn_mfma_f32_16x16x32_bf16(ones, pf[1][0].v, lacc[1], 0, 0, 0);
  lacc[1] = __builtin_amdgcn_mfma_f32_16x16x32_bf16(ones, pf[1][1].v, lacc[1], 0, 0, 0);
  __builtin_amdgcn_s_setprio(0);
}

// normalize by l (lane-local per mq) and write O via per-wave LDS transpose (32 rows)
DEV void attn_epi32(f32x4 (&oacc)[4][2], f32x4 (&lacc)[2],
                    unsigned short* __restrict__ scr,
                    unsigned short* __restrict__ O, int b, int hh, int qw0,
                    int lane, int lo, int hi) {
  const float inv0 = 1.f / lacc[0][0];
  const float inv1 = 1.f / lacc[1][0];
#pragma unroll
  for (int et = 0; et < 4; ++et) {
    f32x4 o0 = oacc[et][0] * inv0;
    f32x4 o1 = oacc[et][1] * inv1;
    u32x2 d0 = {cvtpk(o0[0], o0[1]), cvtpk(o0[2], o0[3])};
    u32x2 d1 = {cvtpk(o1[0], o1[1]), cvtpk(o1[2], o1[3])};
    *(u32x2*)&scr[(0 * 16 + lo) * 72 + et * 16 + hi * 4] = d0;
    *(u32x2*)&scr[(1 * 16 + lo) * 72 + et * 16 + hi * 4] = d1;
  }
  int q = lane & 31, half = lane >> 5;
  unsigned short* dst = O + ((size_t)b * Sseq + qw0 + q) * Dm + hh * HSn + half * 32;
#pragma unroll
  for (int i = 0; i < 4; ++i)
    *(s16x8*)(dst + i * 8) = *(const s16x8*)&scr[q * 72 + half * 32 + i * 8];
}

__global__ __launch_bounds__(256, 2) void attn_kernel(const unsigned short* __restrict__ Q,
                                                      const unsigned short* __restrict__ Kg,
                                                      const unsigned short* __restrict__ Vt,
                                                      unsigned short* __restrict__ O,
                                                      const int* __restrict__ pad,
                                                      const int* __restrict__ tmask,
                                                      const int* __restrict__ flags) {
  __shared__ unsigned short kb[2][64 * 72];   // 18.0 KiB (epilogue reuses as scratch)
  __shared__ unsigned short vb[2][64 * 72];   // 18.0 KiB

  const int ip = blockIdx.y, bh = blockIdx.x; // bh fastest -> same-bh blocks on one XCD
  const int b = bh >> 4, hh = bh & 15;
  const int tid = threadIdx.x, w = tid >> 6, lane = tid & 63, lo = lane & 15, hi = lane >> 4;
  const int qtA = ip, qtB = 15 - ip;
  const int qw0A = qtA * 128 + w * 32, qw0B = qtB * 128 + w * 32;
  const int ktA = 2 * qtA + 1;       // last K-tile index tile A needs (block-uniform)
  const int ktmax = 2 * qtB + 2;     // number of K-tiles tile B needs
  const bool trivial = flags[0] == 0;

  const unsigned short* Qb = Q + (size_t)bh * Sseq * HSn;
  const unsigned short* Kb = Kg + (size_t)bh * Sseq * HSn;
  const unsigned short* Vb = Vt + (size_t)bh * HSn * Sseq;

  // Q fragments for both mq subtiles of each tile (B-operand of swapped QK^T)
  s16x8 qfA[2][2], qfB[2][2];
#pragma unroll
  for (int mq = 0; mq < 2; ++mq)
#pragma unroll
    for (int kk = 0; kk < 2; ++kk) {
      qfA[mq][kk] = *(const s16x8*)&Qb[(size_t)(qw0A + mq * 16 + lo) * HSn + kk * 32 + hi * 8];
      qfB[mq][kk] = *(const s16x8*)&Qb[(size_t)(qw0B + mq * 16 + lo) * HSn + kk * 32 + hi * 8];
    }

  s16x8 ones;
#pragma unroll
  for (int j = 0; j < 8; ++j) ones[j] = (short)0x3F80; // bf16 1.0

  f32x4 oaccA[4][2] = {}, oaccB[4][2] = {};
  f32x4 laccA[2] = {}, laccB[2] = {};
  float mrunA[2] = {-3e38f, -3e38f}, mrunB[2] = {-3e38f, -3e38f};

  // staging (256 threads): each thread loads 32B of K (bit-permuted rows) and 32B of V
  const int sr = tid >> 2, sc = (tid & 3) * 16;
  const int srK = ((sr & 0x1C) << 1) | ((sr & 0x20) >> 3) | (sr & 3);

  // prologue: stage kt=0 into buffer 0
  s16x8 rk0, rk1, rv0, rv1;
  {
    const unsigned short* gk = Kb + (size_t)srK * HSn + sc;
    rk0 = *(const s16x8*)gk; rk1 = *(const s16x8*)(gk + 8);
    const unsigned short* gv = Vb + (size_t)sr * Sseq + sc;
    rv0 = *(const s16x8*)gv; rv1 = *(const s16x8*)(gv + 8);
  }
  *(s16x8*)&kb[0][sr * 72 + sc] = rk0; *(s16x8*)&kb[0][sr * 72 + sc + 8] = rk1;
  *(s16x8*)&vb[0][sr * 72 + sc] = rv0; *(s16x8*)&vb[0][sr * 72 + sc + 8] = rv1;
  __syncthreads();

  for (int kt = 0; kt < ktmax; ++kt) {
    const int cur = kt & 1, k0 = kt * 64;
    const bool pre = (kt + 1 < ktmax);
    if (pre) { // issue next-tile loads early; latency hides under compute
      const int k1 = k0 + 64;
      const unsigned short* gk = Kb + (size_t)(k1 + srK) * HSn + sc;
      rk0 = *(const s16x8*)gk; rk1 = *(const s16x8*)(gk + 8);
      const unsigned short* gv = Vb + (size_t)sr * Sseq + k1 + sc;
      rv0 = *(const s16x8*)gv; rv1 = *(const s16x8*)(gv + 8);
    }
    const unsigned short* kbc = kb[cur];
    const unsigned short* vbc = vb[cur];
    if (kt <= ktA)
      attn_unit32(kbc, vbc, qfA, oaccA, laccA, mrunA, ones,
                  k0, qw0A, lo, hi, b, pad, tmask, trivial);
    attn_unit32(kbc, vbc, qfB, oaccB, laccB, mrunB, ones,
                k0, qw0B, lo, hi, b, pad, tmask, trivial);
    if (pre) { // write-late into the other buffer
      const int nb = cur ^ 1;
      *(s16x8*)&kb[nb][sr * 72 + sc] = rk0; *(s16x8*)&kb[nb][sr * 72 + sc + 8] = rk1;
      *(s16x8*)&vb[nb][sr * 72 + sc] = rv0; *(s16x8*)&vb[nb][sr * 72 + sc + 8] = rv1;
    }
    __syncthreads();
  }

  // epilogue: per-wave scratch carved out of kb (4 waves x 2304 shorts = 9216 = |kb|)
  unsigned short* scr = (unsigned short*)kb + (size_t)w * 2304;
  attn_epi32(oaccA, laccA, scr, O, b, hh, qw0A, lane, lo, hi);
  attn_epi32(oaccB, laccB, scr, O, b, hh, qw0B, lane, lo, hi);
}

extern "C" void kernel_launch(void* const* d_in, const int* in_sizes, int n_in,
                              void* d_out, int out_size, void* d_ws, size_t ws_size,
                              hipStream_t stream) {
  const float* x = (const float*)d_in[0];
  const float* y = (const float*)d_in[1];
  const int* pad = (const int*)d_in[2];
  const int* tmask = (const int*)d_in[3];
  const float* Wq = (const float*)d_in[4];
  const float* Wk = (const float*)d_in[5];
  const float* Wv = (const float*)d_in[6];
  const float* Wp = (const float*)d_in[7];
  const float* bp = (const float*)d_in[8];

  char* ws = (char*)d_ws;
  unsigned short* xbf = (unsigned short*)(ws + OFF_XBF);
  unsigned short* ybf = (unsigned short*)(ws + OFF_YBF);
  unsigned short* wqb = (unsigned short*)(ws + OFF_WQ);
  unsigned short* wkb = (unsigned short*)(ws + OFF_WK);
  unsigned short* wvb = (unsigned short*)(ws + OFF_WV);
  unsigned short* wpb = (unsigned short*)(ws + OFF_WP);
  unsigned short* qws = (unsigned short*)(ws + OFF_QWS);
  unsigned short* kws = (unsigned short*)(ws + OFF_KWS);
  unsigned short* vtw = (unsigned short*)(ws + OFF_VTWS);
  unsigned short* ows = (unsigned short*)(ws + OFF_OWS);
  int* flags = (int*)(ws + OFF_FLAG);

  hipMemsetAsync(flags, 0, 4, stream);
  cvt_all<<<12296, 256, 0, stream>>>(x, y, Wq, Wk, Wv, Wp, pad, tmask, ws, flags);

  q_gemm<<<dim3(64, 8), 256, 0, stream>>>(ybf, wqb, qws);
  kv_gemm<<<dim3(64, 8), 256, 0, stream>>>(xbf, wkb, wvb, kws, vtw);

  attn_kernel<<<dim3(64, 8), 256, 0, stream>>>(qws, kws, vtw, ows, pad, tmask, flags);

  gemm_p<<<dim3(64, 8), 256, 0, stream>>>(ows, wpb, (float*)d_out, bp);
}

// Round 18
// 181.055 us; speedup vs baseline: 1.0270x; 1.0270x over previous
//
#include <hip/hip_runtime.h>
#include <hip/hip_bf16.h>
#include <stdint.h>
#include <stddef.h>

// MultiHA: y@Wq^T -> q; x@Wk^T -> k; x@Wv^T -> v; causal softmax attn; @Wp^T + bp
// B=4 S=2048 D=1024 NH=16 HS=64. All GEMM/attn compute in bf16 MFMA, f32 accum.

typedef __attribute__((ext_vector_type(4))) float f32x4;
typedef __attribute__((ext_vector_type(8))) short s16x8;
typedef __attribute__((ext_vector_type(4))) float float4v;
typedef __attribute__((ext_vector_type(4))) int i32x4;
typedef __attribute__((ext_vector_type(2))) unsigned int u32x2;

#define DEV __device__ __forceinline__

constexpr int Bsz = 4, Sseq = 2048, Dm = 1024, NHn = 16, HSn = 64;
// fold 1/sqrt(HS) * log2(e) into Wq so attention softmax runs in exp2 domain
constexpr float QSCALE = 0.125f * 1.4426950408889634f;

// ---- workspace layout (bytes) ----
constexpr size_t SZ_BF_XY = (size_t)Bsz * Sseq * Dm * 2;  // 16 MiB
constexpr size_t SZ_W     = (size_t)Dm * Dm * 2;          // 2 MiB
constexpr size_t OFF_XBF  = 0;
constexpr size_t OFF_YBF  = OFF_XBF + SZ_BF_XY;
constexpr size_t OFF_WQ   = OFF_YBF + SZ_BF_XY;
constexpr size_t OFF_WK   = OFF_WQ + SZ_W;
constexpr size_t OFF_WV   = OFF_WK + SZ_W;
constexpr size_t OFF_WP   = OFF_WV + SZ_W;
constexpr size_t OFF_QWS  = OFF_WP + SZ_W;   // [BH][S][64] bf16
constexpr size_t OFF_KWS  = OFF_QWS + SZ_BF_XY;
constexpr size_t OFF_VTWS = OFF_KWS + SZ_BF_XY; // [BH][64][S] bf16 (V transposed)
constexpr size_t OFF_OWS  = OFF_VTWS + SZ_BF_XY; // attn out [B][S][D] bf16
constexpr size_t OFF_FLAG = OFF_OWS + SZ_BF_XY;

DEV unsigned short f2bf(float f) {
  union { float f; unsigned int u; } v; v.f = f;
  unsigned int r = (v.u + 0x7FFFu + ((v.u >> 16) & 1u)) >> 16;
  return (unsigned short)r;
}

DEV void gll16(const void* g, void* l) {
  __builtin_amdgcn_global_load_lds((const __attribute__((address_space(1))) unsigned int*)g,
                                   (__attribute__((address_space(3))) unsigned int*)l, 16, 0, 0);
}

DEV unsigned int cvtpk(float a, float b) {
  unsigned int r;
  asm("v_cvt_pk_bf16_f32 %0, %1, %2" : "=v"(r) : "v"(a), "v"(b));
  return r;
}

union U8 { s16x8 v; unsigned int u[4]; };

// ------ fused fp32->bf16 conversion of all inputs + pad/tmask triviality check ------
__global__ void cvt_all(const float* __restrict__ x, const float* __restrict__ y,
                        const float* __restrict__ Wq, const float* __restrict__ Wk,
                        const float* __restrict__ Wv, const float* __restrict__ Wp,
                        const int* __restrict__ pad, const int* __restrict__ tmask,
                        char* __restrict__ ws, int* __restrict__ flags) {
  const int blk = blockIdx.x;
  if (blk >= 10240) {
    int bad = 0;
    if (blk < 10248) { // pad: 8192 ints, 4 per thread
      const i32x4 v = ((const i32x4*)pad)[(blk - 10240) * 256 + threadIdx.x];
      bad = (v[0] == 0) | (v[1] == 0) | (v[2] == 0) | (v[3] == 0);
    } else { // tmask: 4M ints, 8 per thread
      const i32x4* tp = (const i32x4*)tmask + ((size_t)(blk - 10248) * 256 + threadIdx.x) * 2;
      i32x4 v0 = tp[0], v1 = tp[1];
      bad = (v0[0] == 0) | (v0[1] == 0) | (v0[2] == 0) | (v0[3] == 0) |
            (v1[0] == 0) | (v1[1] == 0) | (v1[2] == 0) | (v1[3] == 0);
    }
    if (__builtin_amdgcn_ballot_w64(bad) != 0 && (threadIdx.x & 63) == 0)
      atomicOr(flags, 1);
    return;
  }
  const float* src;
  unsigned short* dst;
  int b8;
  float scale = 1.f;
  if (blk < 4096)      { src = x;  dst = (unsigned short*)(ws + OFF_XBF); b8 = blk; }
  else if (blk < 8192) { src = y;  dst = (unsigned short*)(ws + OFF_YBF); b8 = blk - 4096; }
  else if (blk < 8704) { src = Wq; dst = (unsigned short*)(ws + OFF_WQ);  b8 = blk - 8192; scale = QSCALE; }
  else if (blk < 9216) { src = Wk; dst = (unsigned short*)(ws + OFF_WK);  b8 = blk - 8704; }
  else if (blk < 9728) { src = Wv; dst = (unsigned short*)(ws + OFF_WV);  b8 = blk - 9216; }
  else                 { src = Wp; dst = (unsigned short*)(ws + OFF_WP);  b8 = blk - 9728; }
  const size_t i = (size_t)b8 * 256 + threadIdx.x;
  const float4v* s = (const float4v*)src + i * 2;
  float4v a = s[0], b = s[1];
  s16x8 o;
  o[0] = (short)f2bf(a[0] * scale); o[1] = (short)f2bf(a[1] * scale);
  o[2] = (short)f2bf(a[2] * scale); o[3] = (short)f2bf(a[3] * scale);
  o[4] = (short)f2bf(b[0] * scale); o[5] = (short)f2bf(b[1] * scale);
  o[6] = (short)f2bf(b[2] * scale); o[7] = (short)f2bf(b[3] * scale);
  *(s16x8*)(dst + i * 8) = o;
}

// ------ Q projection GEMM: 128x128 tile, 8 waves (2x4), 2-phase double-buffer --------
// Wave w: rows wm*64 (wm=w>>2), cols wn*32 (wn=w&3); acc[4][2] fragments.
__global__ __launch_bounds__(512, 4) void q_gemm(const unsigned short* __restrict__ A,
                                                 const unsigned short* __restrict__ W,
                                                 unsigned short* __restrict__ outb) {
  constexpr int K = 1024;
  __shared__ unsigned short sm[2][8192]; // [buf][lA 4096 | lB 4096]
  const int tid = threadIdx.x;
  const int w = tid >> 6, lane = tid & 63, lo = lane & 15, hi = lane >> 4;
  const int wm = w >> 2, wn = w & 3;
  const int m0 = blockIdx.x * 128, n0 = blockIdx.y * 128;
  f32x4 acc[4][2] = {};

  auto stage = [&](int buf, int k0) {
    gll16(A + (size_t)(m0 + (tid >> 2)) * K + k0 + (tid & 3) * 8, &sm[buf][0] + (size_t)tid * 8);
    gll16(W + (size_t)(n0 + (tid >> 2)) * K + k0 + (tid & 3) * 8, &sm[buf][4096] + (size_t)tid * 8);
  };

  stage(0, 0);
  __syncthreads(); // drains vmcnt -> buf0 ready
  for (int t = 0; t < 32; ++t) {
    if (t < 31) stage((t + 1) & 1, (t + 1) * 32); // issue next tile early
    const unsigned short* lA = &sm[t & 1][0];
    const unsigned short* lB = &sm[t & 1][4096];
    s16x8 af[4], bfr[2];
#pragma unroll
    for (int mi = 0; mi < 4; ++mi) af[mi] = *(const s16x8*)&lA[(wm * 64 + mi * 16 + lo) * 32 + hi * 8];
#pragma unroll
    for (int ni = 0; ni < 2; ++ni) bfr[ni] = *(const s16x8*)&lB[(wn * 32 + ni * 16 + lo) * 32 + hi * 8];
#pragma unroll
    for (int mi = 0; mi < 4; ++mi)
#pragma unroll
      for (int ni = 0; ni < 2; ++ni)
        acc[mi][ni] = __builtin_amdgcn_mfma_f32_16x16x32_bf16(af[mi], bfr[ni], acc[mi][ni], 0, 0, 0);
    __syncthreads(); // readers done + next-tile loads drained
  }
#pragma unroll
  for (int mi = 0; mi < 4; ++mi)
#pragma unroll
    for (int ni = 0; ni < 2; ++ni)
#pragma unroll
      for (int j = 0; j < 4; ++j) {
        int m = m0 + wm * 64 + mi * 16 + hi * 4 + j;
        int n = n0 + wn * 32 + ni * 16 + lo;
        int b = m >> 11, s = m & 2047, hh = n >> 6, e = n & 63;
        outb[((size_t)(b * NHn + hh) * Sseq + s) * HSn + e] = f2bf(acc[mi][ni][j]);
      }
}

// ------ merged K+V projection GEMM: 8 waves (2x4), shared x staging, 2-phase ---------
__global__ __launch_bounds__(512, 4) void kv_gemm(const unsigned short* __restrict__ A,
                                                  const unsigned short* __restrict__ Wk,
                                                  const unsigned short* __restrict__ Wv,
                                                  unsigned short* __restrict__ kws,
                                                  unsigned short* __restrict__ vtw) {
  constexpr int K = 1024;
  __shared__ unsigned short sm[2][12288]; // [buf][lA | lBk | lBv]; epilogue reuses flat
  const int tid = threadIdx.x;
  const int w = tid >> 6, lane = tid & 63, lo = lane & 15, hi = lane >> 4;
  const int wm = w >> 2, wn = w & 3;
  const int m0 = blockIdx.x * 128, n0 = blockIdx.y * 128;
  f32x4 acck[4][2] = {}, accv[4][2] = {};

  auto stage = [&](int buf, int k0) {
    size_t roff = (size_t)(tid >> 2) * K + k0 + (tid & 3) * 8;
    size_t loff = (size_t)tid * 8;
    gll16(A + (size_t)m0 * K + roff, &sm[buf][0] + loff);
    gll16(Wk + (size_t)n0 * K + roff, &sm[buf][4096] + loff);
    gll16(Wv + (size_t)n0 * K + roff, &sm[buf][8192] + loff);
  };

  stage(0, 0);
  __syncthreads();
  for (int t = 0; t < 32; ++t) {
    if (t < 31) stage((t + 1) & 1, (t + 1) * 32);
    const unsigned short* lA = &sm[t & 1][0];
    const unsigned short* lBk = &sm[t & 1][4096];
    const unsigned short* lBv = &sm[t & 1][8192];
    s16x8 af[4], bfk[2], bfv[2];
#pragma unroll
    for (int mi = 0; mi < 4; ++mi) af[mi] = *(const s16x8*)&lA[(wm * 64 + mi * 16 + lo) * 32 + hi * 8];
#pragma unroll
    for (int ni = 0; ni < 2; ++ni) {
      bfk[ni] = *(const s16x8*)&lBk[(wn * 32 + ni * 16 + lo) * 32 + hi * 8];
      bfv[ni] = *(const s16x8*)&lBv[(wn * 32 + ni * 16 + lo) * 32 + hi * 8];
    }
#pragma unroll
    for (int mi = 0; mi < 4; ++mi)
#pragma unroll
      for (int ni = 0; ni < 2; ++ni) {
        acck[mi][ni] = __builtin_amdgcn_mfma_f32_16x16x32_bf16(af[mi], bfk[ni], acck[mi][ni], 0, 0, 0);
        accv[mi][ni] = __builtin_amdgcn_mfma_f32_16x16x32_bf16(af[mi], bfv[ni], accv[mi][ni], 0, 0, 0);
      }
    __syncthreads();
  }

  // K epilogue: direct global stores
#pragma unroll
  for (int mi = 0; mi < 4; ++mi)
#pragma unroll
    for (int ni = 0; ni < 2; ++ni)
#pragma unroll
      for (int j = 0; j < 4; ++j) {
        int m = m0 + wm * 64 + mi * 16 + hi * 4 + j;
        int n = n0 + wn * 32 + ni * 16 + lo;
        int b = m >> 11, s = m & 2047, hh = n >> 6, e = n & 63;
        kws[((size_t)(b * NHn + hh) * Sseq + s) * HSn + e] = f2bf(acck[mi][ni][j]);
      }
  // V epilogue: LDS transpose (reuses sm flat: needs 17408 shorts < 24576)
  unsigned short* tp = &sm[0][0];
  __syncthreads();
#pragma unroll
  for (int mi = 0; mi < 4; ++mi)
#pragma unroll
    for (int ni = 0; ni < 2; ++ni)
#pragma unroll
      for (int j = 0; j < 4; ++j) {
        int ml = wm * 64 + mi * 16 + hi * 4 + j;
        int nl = wn * 32 + ni * 16 + lo;
        tp[(size_t)nl * 136 + ml] = f2bf(accv[mi][ni][j]);
      }
  __syncthreads();
  int nl = tid >> 2, seg = tid & 3;
  int b = m0 >> 11, hh = (n0 + nl) >> 6, e = (n0 + nl) & 63;
  unsigned short* dst = vtw + ((size_t)(b * NHn + hh) * HSn + e) * Sseq + (m0 & 2047) + seg * 32;
#pragma unroll
  for (int i = 0; i < 4; ++i)
    *(s16x8*)(dst + i * 8) = *(const s16x8*)&tp[(size_t)nl * 136 + seg * 32 + i * 8];
}

// ------ final projection GEMM: 8 waves (2x4), fp32 out [M][1024] + bias --------------
__global__ __launch_bounds__(512, 4) void gemm_p(const unsigned short* __restrict__ A,
                                                 const unsigned short* __restrict__ W,
                                                 float* __restrict__ outf,
                                                 const float* __restrict__ bias) {
  constexpr int K = 1024;
  __shared__ unsigned short sm[2][8192];
  const int tid = threadIdx.x;
  const int w = tid >> 6, lane = tid & 63, lo = lane & 15, hi = lane >> 4;
  const int wm = w >> 2, wn = w & 3;
  const int m0 = blockIdx.x * 128, n0 = blockIdx.y * 128;
  f32x4 acc[4][2] = {};

  auto stage = [&](int buf, int k0) {
    gll16(A + (size_t)(m0 + (tid >> 2)) * K + k0 + (tid & 3) * 8, &sm[buf][0] + (size_t)tid * 8);
    gll16(W + (size_t)(n0 + (tid >> 2)) * K + k0 + (tid & 3) * 8, &sm[buf][4096] + (size_t)tid * 8);
  };

  stage(0, 0);
  __syncthreads();
  for (int t = 0; t < 32; ++t) {
    if (t < 31) stage((t + 1) & 1, (t + 1) * 32);
    const unsigned short* lA = &sm[t & 1][0];
    const unsigned short* lB = &sm[t & 1][4096];
    s16x8 af[4], bfr[2];
#pragma unroll
    for (int mi = 0; mi < 4; ++mi) af[mi] = *(const s16x8*)&lA[(wm * 64 + mi * 16 + lo) * 32 + hi * 8];
#pragma unroll
    for (int ni = 0; ni < 2; ++ni) bfr[ni] = *(const s16x8*)&lB[(wn * 32 + ni * 16 + lo) * 32 + hi * 8];
#pragma unroll
    for (int mi = 0; mi < 4; ++mi)
#pragma unroll
      for (int ni = 0; ni < 2; ++ni)
        acc[mi][ni] = __builtin_amdgcn_mfma_f32_16x16x32_bf16(af[mi], bfr[ni], acc[mi][ni], 0, 0, 0);
    __syncthreads();
  }
  float bv[2];
#pragma unroll
  for (int ni = 0; ni < 2; ++ni) bv[ni] = bias[n0 + wn * 32 + ni * 16 + lo];
#pragma unroll
  for (int mi = 0; mi < 4; ++mi)
#pragma unroll
    for (int ni = 0; ni < 2; ++ni)
#pragma unroll
      for (int j = 0; j < 4; ++j) {
        int m = m0 + wm * 64 + mi * 16 + hi * 4 + j;
        int n = n0 + wn * 32 + ni * 16 + lo;
        outf[(size_t)m * 1024 + n] = acc[mi][ni][j] + bv[ni];
      }
}

// ---------------- flash attention (R16-verified: 8-wave, permuted-K, in-reg P) --------
// K rows staged bit-permuted: storage row s holds logical ((s&0x1C)<<1)|((s&0x20)>>3)|(s&3).
// QK^T slot (t,hi,j) = logical kpos 32(t&1)+8hi+4(t>>1)+j; PV B-fragment is a pure
// register rearrangement of packed P (zero-LDS P path). Defer-max (thr=11, exp2 domain)
// + l via ones-MFMA. setprio(1) wraps MFMA clusters.
DEV void attn_unit16(const unsigned short* __restrict__ kbc,
                     const unsigned short* __restrict__ vbc,
                     const s16x8 (&qf)[2], f32x4 (&oacc)[4], f32x4& lacc,
                     float& mrun, const s16x8& ones,
                     int k0, int qw0, int lo, int hi, int b,
                     const int* __restrict__ pad, const int* __restrict__ tmask,
                     bool trivial) {
  if (k0 > qw0 + 15) return; // wave-uniform: tile entirely above this wave's rows

  // S^T = K Q^T (operand-swapped; K rows permuted in LDS)
  f32x4 st[4];
  __builtin_amdgcn_s_setprio(1);
#pragma unroll
  for (int t = 0; t < 4; ++t) {
    f32x4 z = {0.f, 0.f, 0.f, 0.f};
#pragma unroll
    for (int kk = 0; kk < 2; ++kk) {
      s16x8 kfr = *(const s16x8*)&kbc[(t * 16 + lo) * 72 + kk * 32 + hi * 8];
      z = __builtin_amdgcn_mfma_f32_16x16x32_bf16(kfr, qf[kk], z, 0, 0, 0);
    }
    st[t] = z;
  }
  __builtin_amdgcn_s_setprio(0);
  const int qg = qw0 + lo;
  const int kgb = k0 + hi * 8; // logical kpos base for this lane's slots
  if (k0 + 63 > qw0) { // diagonal tiles: causal mask (logical kpos > q)
#pragma unroll
    for (int t = 0; t < 4; ++t)
#pragma unroll
      for (int j = 0; j < 4; ++j) {
        int kg = kgb + ((t & 1) << 5) + ((t >> 1) << 2) + j;
        if (kg > qg) st[t][j] = -3e38f;
      }
  }
  if (!trivial) { // general pad/time masks (not hit for all-ones inputs)
#pragma unroll
    for (int t = 0; t < 4; ++t)
#pragma unroll
      for (int j = 0; j < 4; ++j) {
        int kg = kgb + ((t & 1) << 5) + ((t >> 1) << 2) + j;
        if (!pad[b * Sseq + kg] || !tmask[(size_t)qg * Sseq + kg]) st[t][j] = -3e38f;
      }
  }
  // tile max for this lane's q-column (lane-local + 2 shuffles over hi-groups)
  float m0v = fmaxf(fmaxf(st[0][0], st[0][1]), fmaxf(st[0][2], st[0][3]));
  float m1v = fmaxf(fmaxf(st[1][0], st[1][1]), fmaxf(st[1][2], st[1][3]));
  float m2v = fmaxf(fmaxf(st[2][0], st[2][1]), fmaxf(st[2][2], st[2][3]));
  float m3v = fmaxf(fmaxf(st[3][0], st[3][1]), fmaxf(st[3][2], st[3][3]));
  float mx = fmaxf(fmaxf(m0v, m1v), fmaxf(m2v, m3v));
  mx = fmaxf(mx, __shfl_xor(mx, 16, 64));
  mx = fmaxf(mx, __shfl_xor(mx, 32, 64));
  // defer-max: only rescale when the bound would be exceeded (P <= 2^11 otherwise)
  if (!__all(mx <= mrun + 11.f)) {
    const float mnew = fmaxf(mrun, mx);
    const float al = __builtin_amdgcn_exp2f(mrun - mnew);
    mrun = mnew;
#pragma unroll
    for (int et = 0; et < 4; ++et) oacc[et] *= al;
    lacc *= al;
  }
  // P = exp2(S - mrun), packed to bf16 pairs in registers
  unsigned int pk[4][2];
#pragma unroll
  for (int t = 0; t < 4; ++t) {
    float p0 = __builtin_amdgcn_exp2f(st[t][0] - mrun);
    float p1 = __builtin_amdgcn_exp2f(st[t][1] - mrun);
    float p2 = __builtin_amdgcn_exp2f(st[t][2] - mrun);
    float p3 = __builtin_amdgcn_exp2f(st[t][3] - mrun);
    pk[t][0] = cvtpk(p0, p1);
    pk[t][1] = cvtpk(p2, p3);
  }
  // assemble PV B-fragments in registers (kpos = kk*32 + hi*8 + 0..7, col q = lo)
  U8 pf0, pf1;
  pf0.u[0] = pk[0][0]; pf0.u[1] = pk[0][1]; pf0.u[2] = pk[2][0]; pf0.u[3] = pk[2][1];
  pf1.u[0] = pk[1][0]; pf1.u[1] = pk[1][1]; pf1.u[2] = pk[3][0]; pf1.u[3] = pk[3][1];
  // O^T += V^T P^T ; l += ones . P (all rows of lacc equal l[q])
  __builtin_amdgcn_s_setprio(1);
#pragma unroll
  for (int et = 0; et < 4; ++et) {
    s16x8 vf0 = *(const s16x8*)&vbc[(et * 16 + lo) * 72 + hi * 8];
    s16x8 vf1 = *(const s16x8*)&vbc[(et * 16 + lo) * 72 + 32 + hi * 8];
    oacc[et] = __builtin_amdgcn_mfma_f32_16x16x32_bf16(vf0, pf0.v, oacc[et], 0, 0, 0);
    oacc[et] = __builtin_amdgcn_mfma_f32_16x16x32_bf16(vf1, pf1.v, oacc[et], 0, 0, 0);
  }
  lacc = __builtin_amdgcn_mfma_f32_16x16x32_bf16(ones, pf0.v, lacc, 0, 0, 0);
  lacc = __builtin_amdgcn_mfma_f32_16x16x32_bf16(ones, pf1.v, lacc, 0, 0, 0);
  __builtin_amdgcn_s_setprio(0);
}

// normalize by l (lane-local) and write O via per-wave LDS transpose (16 rows)
DEV void attn_epi16(f32x4 (&oacc)[4], float lrun,
                    unsigned short* __restrict__ scr,
                    unsigned short* __restrict__ O, int b, int hh, int qw0,
                    int lane, int lo, int hi) {
  const float inv = 1.f / lrun;
#pragma unroll
  for (int et = 0; et < 4; ++et) {
    f32x4 o = oacc[et] * inv;
    u32x2 d = {cvtpk(o[0], o[1]), cvtpk(o[2], o[3])};
    *(u32x2*)&scr[lo * 72 + et * 16 + hi * 4] = d;
  }
  int q = lane >> 2, seg = lane & 3;
  unsigned short* dst = O + ((size_t)b * Sseq + qw0 + q) * Dm + hh * HSn + seg * 16;
  *(s16x8*)dst = *(const s16x8*)&scr[q * 72 + seg * 16];
  *(s16x8*)(dst + 8) = *(const s16x8*)&scr[q * 72 + seg * 16 + 8];
}

__global__ __launch_bounds__(512, 4) void attn_kernel(const unsigned short* __restrict__ Q,
                                                      const unsigned short* __restrict__ Kg,
                                                      const unsigned short* __restrict__ Vt,
                                                      unsigned short* __restrict__ O,
                                                      const int* __restrict__ pad,
                                                      const int* __restrict__ tmask,
                                                      const int* __restrict__ flags) {
  __shared__ unsigned short kb[2][64 * 72];   // 18.0 KiB (epilogue reuses as scratch)
  __shared__ unsigned short vb[2][64 * 72];   // 18.0 KiB

  const int ip = blockIdx.y, bh = blockIdx.x; // bh fastest -> same-bh blocks on one XCD
  const int b = bh >> 4, hh = bh & 15;
  const int tid = threadIdx.x, w = tid >> 6, lane = tid & 63, lo = lane & 15, hi = lane >> 4;
  const int qtA = ip, qtB = 15 - ip;
  const int qw0A = qtA * 128 + w * 16, qw0B = qtB * 128 + w * 16;
  const int ktA = 2 * qtA + 1;       // last K-tile index tile A needs (any wave)
  const int ktmax = 2 * qtB + 2;     // number of K-tiles tile B needs
  const bool trivial = flags[0] == 0;

  const unsigned short* Qb = Q + (size_t)bh * Sseq * HSn;
  const unsigned short* Kb = Kg + (size_t)bh * Sseq * HSn;
  const unsigned short* Vb = Vt + (size_t)bh * HSn * Sseq;

  // Q fragments (B-operand of swapped QK^T)
  s16x8 qfA[2], qfB[2];
#pragma unroll
  for (int kk = 0; kk < 2; ++kk) {
    qfA[kk] = *(const s16x8*)&Qb[(size_t)(qw0A + lo) * HSn + kk * 32 + hi * 8];
    qfB[kk] = *(const s16x8*)&Qb[(size_t)(qw0B + lo) * HSn + kk * 32 + hi * 8];
  }

  s16x8 ones;
#pragma unroll
  for (int j = 0; j < 8; ++j) ones[j] = (short)0x3F80; // bf16 1.0

  f32x4 oaccA[4] = {}, oaccB[4] = {};
  f32x4 laccA = {}, laccB = {};
  float mrunA = -3e38f, mrunB = -3e38f;

  // staging: waves 0-3 handle K (bit-permuted row order), waves 4-7 handle V
  const int shalf = tid >> 8, st_t = tid & 255;
  const int sr = st_t >> 2, sc = (st_t & 3) * 16;
  // logical K row for storage row sr: L = [s4 s3 s2 | s5 | s1 s0]
  const int srK = ((sr & 0x1C) << 1) | ((sr & 0x20) >> 3) | (sr & 3);

  // prologue: stage kt=0 into buffer 0
  s16x8 r0, r1;
  if (shalf == 0) {
    const unsigned short* gk = Kb + (size_t)srK * HSn + sc;
    r0 = *(const s16x8*)gk; r1 = *(const s16x8*)(gk + 8);
    *(s16x8*)&kb[0][sr * 72 + sc] = r0; *(s16x8*)&kb[0][sr * 72 + sc + 8] = r1;
  } else {
    const unsigned short* gv = Vb + (size_t)sr * Sseq + sc;
    r0 = *(const s16x8*)gv; r1 = *(const s16x8*)(gv + 8);
    *(s16x8*)&vb[0][sr * 72 + sc] = r0; *(s16x8*)&vb[0][sr * 72 + sc + 8] = r1;
  }
  __syncthreads();

  for (int kt = 0; kt < ktmax; ++kt) {
    const int cur = kt & 1, k0 = kt * 64;
    const bool pre = (kt + 1 < ktmax);
    if (pre) { // issue next-tile loads early; latency hides under compute
      const int k1 = k0 + 64;
      if (shalf == 0) {
        const unsigned short* gk = Kb + (size_t)(k1 + srK) * HSn + sc;
        r0 = *(const s16x8*)gk; r1 = *(const s16x8*)(gk + 8);
      } else {
        const unsigned short* gv = Vb + (size_t)sr * Sseq + k1 + sc;
        r0 = *(const s16x8*)gv; r1 = *(const s16x8*)(gv + 8);
      }
    }
    const unsigned short* kbc = kb[cur];
    const unsigned short* vbc = vb[cur];
    if (kt <= ktA)
      attn_unit16(kbc, vbc, qfA, oaccA, laccA, mrunA, ones,
                  k0, qw0A, lo, hi, b, pad, tmask, trivial);
    attn_unit16(kbc, vbc, qfB, oaccB, laccB, mrunB, ones,
                k0, qw0B, lo, hi, b, pad, tmask, trivial);
    if (pre) { // write-late into the other buffer
      const int nb = cur ^ 1;
      if (shalf == 0) {
        *(s16x8*)&kb[nb][sr * 72 + sc] = r0; *(s16x8*)&kb[nb][sr * 72 + sc + 8] = r1;
      } else {
        *(s16x8*)&vb[nb][sr * 72 + sc] = r0; *(s16x8*)&vb[nb][sr * 72 + sc + 8] = r1;
      }
    }
    __syncthreads();
  }

  // epilogue: per-wave scratch carved out of kb (all compute on kb finished above)
  unsigned short* scr = (unsigned short*)kb + (size_t)w * 1152;
  attn_epi16(oaccA, laccA[0], scr, O, b, hh, qw0A, lane, lo, hi);
  attn_epi16(oaccB, laccB[0], scr, O, b, hh, qw0B, lane, lo, hi);
}

extern "C" void kernel_launch(void* const* d_in, const int* in_sizes, int n_in,
                              void* d_out, int out_size, void* d_ws, size_t ws_size,
                              hipStream_t stream) {
  const float* x = (const float*)d_in[0];
  const float* y = (const float*)d_in[1];
  const int* pad = (const int*)d_in[2];
  const int* tmask = (const int*)d_in[3];
  const float* Wq = (const float*)d_in[4];
  const float* Wk = (const float*)d_in[5];
  const float* Wv = (const float*)d_in[6];
  const float* Wp = (const float*)d_in[7];
  const float* bp = (const float*)d_in[8];

  char* ws = (char*)d_ws;
  unsigned short* xbf = (unsigned short*)(ws + OFF_XBF);
  unsigned short* ybf = (unsigned short*)(ws + OFF_YBF);
  unsigned short* wqb = (unsigned short*)(ws + OFF_WQ);
  unsigned short* wkb = (unsigned short*)(ws + OFF_WK);
  unsigned short* wvb = (unsigned short*)(ws + OFF_WV);
  unsigned short* wpb = (unsigned short*)(ws + OFF_WP);
  unsigned short* qws = (unsigned short*)(ws + OFF_QWS);
  unsigned short* kws = (unsigned short*)(ws + OFF_KWS);
  unsigned short* vtw = (unsigned short*)(ws + OFF_VTWS);
  unsigned short* ows = (unsigned short*)(ws + OFF_OWS);
  int* flags = (int*)(ws + OFF_FLAG);

  hipMemsetAsync(flags, 0, 4, stream);
  cvt_all<<<12296, 256, 0, stream>>>(x, y, Wq, Wk, Wv, Wp, pad, tmask, ws, flags);

  q_gemm<<<dim3(64, 8), 512, 0, stream>>>(ybf, wqb, qws);
  kv_gemm<<<dim3(64, 8), 512, 0, stream>>>(xbf, wkb, wvb, kws, vtw);

  attn_kernel<<<dim3(64, 8), 512, 0, stream>>>(qws, kws, vtw, ows, pad, tmask, flags);

  gemm_p<<<dim3(64, 8), 512, 0, stream>>>(ows, wpb, (float*)d_out, bp);
}

// Round 19
// 175.188 us; speedup vs baseline: 1.0614x; 1.0335x over previous
//
#include <hip/hip_runtime.h>
#include <hip/hip_bf16.h>
#include <stdint.h>
#include <stddef.h>

// MultiHA: y@Wq^T -> q; x@Wk^T -> k; x@Wv^T -> v; causal softmax attn; @Wp^T + bp
// B=4 S=2048 D=1024 NH=16 HS=64. All GEMM/attn compute in bf16 MFMA, f32 accum.

typedef __attribute__((ext_vector_type(4))) float f32x4;
typedef __attribute__((ext_vector_type(8))) short s16x8;
typedef __attribute__((ext_vector_type(4))) float float4v;
typedef __attribute__((ext_vector_type(4))) int i32x4;
typedef __attribute__((ext_vector_type(2))) unsigned int u32x2;

#define DEV __device__ __forceinline__

constexpr int Bsz = 4, Sseq = 2048, Dm = 1024, NHn = 16, HSn = 64;
// fold 1/sqrt(HS) * log2(e) into Wq so attention softmax runs in exp2 domain
constexpr float QSCALE = 0.125f * 1.4426950408889634f;

// ---- workspace layout (bytes) ----
constexpr size_t SZ_BF_XY = (size_t)Bsz * Sseq * Dm * 2;  // 16 MiB
constexpr size_t SZ_W     = (size_t)Dm * Dm * 2;          // 2 MiB
constexpr size_t OFF_XBF  = 0;
constexpr size_t OFF_YBF  = OFF_XBF + SZ_BF_XY;
constexpr size_t OFF_WQ   = OFF_YBF + SZ_BF_XY;
constexpr size_t OFF_WK   = OFF_WQ + SZ_W;
constexpr size_t OFF_WV   = OFF_WK + SZ_W;
constexpr size_t OFF_WP   = OFF_WV + SZ_W;
constexpr size_t OFF_QWS  = OFF_WP + SZ_W;   // [BH][S][64] bf16
constexpr size_t OFF_KWS  = OFF_QWS + SZ_BF_XY;
constexpr size_t OFF_VTWS = OFF_KWS + SZ_BF_XY; // [BH][64][S] bf16 (V transposed)
constexpr size_t OFF_OWS  = OFF_VTWS + SZ_BF_XY; // attn out [B][S][D] bf16
constexpr size_t OFF_FLAG = OFF_OWS + SZ_BF_XY;

DEV unsigned short f2bf(float f) {
  union { float f; unsigned int u; } v; v.f = f;
  unsigned int r = (v.u + 0x7FFFu + ((v.u >> 16) & 1u)) >> 16;
  return (unsigned short)r;
}

DEV void gll16(const void* g, void* l) {
  __builtin_amdgcn_global_load_lds((const __attribute__((address_space(1))) unsigned int*)g,
                                   (__attribute__((address_space(3))) unsigned int*)l, 16, 0, 0);
}

DEV unsigned int cvtpk(float a, float b) {
  unsigned int r;
  asm("v_cvt_pk_bf16_f32 %0, %1, %2" : "=v"(r) : "v"(a), "v"(b));
  return r;
}

union U8 { s16x8 v; unsigned int u[4]; };

// ------ fused fp32->bf16 conversion of all inputs + pad/tmask triviality check ------
__global__ void cvt_all(const float* __restrict__ x, const float* __restrict__ y,
                        const float* __restrict__ Wq, const float* __restrict__ Wk,
                        const float* __restrict__ Wv, const float* __restrict__ Wp,
                        const int* __restrict__ pad, const int* __restrict__ tmask,
                        char* __restrict__ ws, int* __restrict__ flags) {
  const int blk = blockIdx.x;
  if (blk >= 10240) {
    int bad = 0;
    if (blk < 10248) { // pad: 8192 ints, 4 per thread
      const i32x4 v = ((const i32x4*)pad)[(blk - 10240) * 256 + threadIdx.x];
      bad = (v[0] == 0) | (v[1] == 0) | (v[2] == 0) | (v[3] == 0);
    } else { // tmask: 4M ints, 8 per thread
      const i32x4* tp = (const i32x4*)tmask + ((size_t)(blk - 10248) * 256 + threadIdx.x) * 2;
      i32x4 v0 = tp[0], v1 = tp[1];
      bad = (v0[0] == 0) | (v0[1] == 0) | (v0[2] == 0) | (v0[3] == 0) |
            (v1[0] == 0) | (v1[1] == 0) | (v1[2] == 0) | (v1[3] == 0);
    }
    if (__builtin_amdgcn_ballot_w64(bad) != 0 && (threadIdx.x & 63) == 0)
      atomicOr(flags, 1);
    return;
  }
  const float* src;
  unsigned short* dst;
  int b8;
  float scale = 1.f;
  if (blk < 4096)      { src = x;  dst = (unsigned short*)(ws + OFF_XBF); b8 = blk; }
  else if (blk < 8192) { src = y;  dst = (unsigned short*)(ws + OFF_YBF); b8 = blk - 4096; }
  else if (blk < 8704) { src = Wq; dst = (unsigned short*)(ws + OFF_WQ);  b8 = blk - 8192; scale = QSCALE; }
  else if (blk < 9216) { src = Wk; dst = (unsigned short*)(ws + OFF_WK);  b8 = blk - 8704; }
  else if (blk < 9728) { src = Wv; dst = (unsigned short*)(ws + OFF_WV);  b8 = blk - 9216; }
  else                 { src = Wp; dst = (unsigned short*)(ws + OFF_WP);  b8 = blk - 9728; }
  const size_t i = (size_t)b8 * 256 + threadIdx.x;
  const float4v* s = (const float4v*)src + i * 2;
  float4v a = s[0], b = s[1];
  s16x8 o;
  o[0] = (short)f2bf(a[0] * scale); o[1] = (short)f2bf(a[1] * scale);
  o[2] = (short)f2bf(a[2] * scale); o[3] = (short)f2bf(a[3] * scale);
  o[4] = (short)f2bf(b[0] * scale); o[5] = (short)f2bf(b[1] * scale);
  o[6] = (short)f2bf(b[2] * scale); o[7] = (short)f2bf(b[3] * scale);
  *(s16x8*)(dst + i * 8) = o;
}

// ------ Q projection GEMM: 128x128 tile, BK=64, 8 waves (2x4), 2-phase dbuf ----------
// T2 swizzle (BK=64 rows are 128B -> 16-way conflict unswizzled): global source
// pre-swizzled seg^=(row&7); fragment reads XOR the same involution on the column.
__global__ __launch_bounds__(512, 4) void q_gemm(const unsigned short* __restrict__ A,
                                                 const unsigned short* __restrict__ W,
                                                 unsigned short* __restrict__ outb) {
  constexpr int K = 1024;
  __shared__ unsigned short sm[2][16384]; // [buf][lA 8192 | lB 8192] shorts (64 KiB)
  const int tid = threadIdx.x;
  const int w = tid >> 6, lane = tid & 63, lo = lane & 15, hi = lane >> 4;
  const int wm = w >> 2, wn = w & 3;
  const int m0 = blockIdx.x * 128, n0 = blockIdx.y * 128;
  f32x4 acc[4][2] = {};

  auto stage = [&](int buf, int k0) {
#pragma unroll
    for (int h = 0; h < 2; ++h) {
      int c = h * 512 + tid;
      int r = c >> 3, sg = (c & 7) ^ (r & 7);   // pre-swizzled source segment
      gll16(A + (size_t)(m0 + r) * K + k0 + sg * 8, &sm[buf][0] + (size_t)c * 8);
      gll16(W + (size_t)(n0 + r) * K + k0 + sg * 8, &sm[buf][8192] + (size_t)c * 8);
    }
  };

  stage(0, 0);
  __syncthreads(); // drains vmcnt -> buf0 ready
  for (int t = 0; t < 16; ++t) {
    if (t < 15) stage((t + 1) & 1, (t + 1) * 64); // issue next tile early
    const unsigned short* lA = &sm[t & 1][0];
    const unsigned short* lB = &sm[t & 1][8192];
    s16x8 af[4][2], bfr[2][2];
#pragma unroll
    for (int mi = 0; mi < 4; ++mi) {
      int r = wm * 64 + mi * 16 + lo;
#pragma unroll
      for (int kk = 0; kk < 2; ++kk)
        af[mi][kk] = *(const s16x8*)&lA[r * 64 + ((kk * 32 + hi * 8) ^ ((r & 7) << 3))];
    }
#pragma unroll
    for (int ni = 0; ni < 2; ++ni) {
      int r = wn * 32 + ni * 16 + lo;
#pragma unroll
      for (int kk = 0; kk < 2; ++kk)
        bfr[ni][kk] = *(const s16x8*)&lB[r * 64 + ((kk * 32 + hi * 8) ^ ((r & 7) << 3))];
    }
#pragma unroll
    for (int mi = 0; mi < 4; ++mi)
#pragma unroll
      for (int ni = 0; ni < 2; ++ni)
#pragma unroll
        for (int kk = 0; kk < 2; ++kk)
          acc[mi][ni] = __builtin_amdgcn_mfma_f32_16x16x32_bf16(af[mi][kk], bfr[ni][kk], acc[mi][ni], 0, 0, 0);
    __syncthreads();
  }
#pragma unroll
  for (int mi = 0; mi < 4; ++mi)
#pragma unroll
    for (int ni = 0; ni < 2; ++ni)
#pragma unroll
      for (int j = 0; j < 4; ++j) {
        int m = m0 + wm * 64 + mi * 16 + hi * 4 + j;
        int n = n0 + wn * 32 + ni * 16 + lo;
        int b = m >> 11, s = m & 2047, hh = n >> 6, e = n & 63;
        outb[((size_t)(b * NHn + hh) * Sseq + s) * HSn + e] = f2bf(acc[mi][ni][j]);
      }
}

// ------ merged K+V projection GEMM: 8 waves (2x4), shared x staging, BK=32 2-phase ---
__global__ __launch_bounds__(512, 4) void kv_gemm(const unsigned short* __restrict__ A,
                                                  const unsigned short* __restrict__ Wk,
                                                  const unsigned short* __restrict__ Wv,
                                                  unsigned short* __restrict__ kws,
                                                  unsigned short* __restrict__ vtw) {
  constexpr int K = 1024;
  __shared__ unsigned short sm[2][12288]; // [buf][lA | lBk | lBv]; epilogue reuses flat
  const int tid = threadIdx.x;
  const int w = tid >> 6, lane = tid & 63, lo = lane & 15, hi = lane >> 4;
  const int wm = w >> 2, wn = w & 3;
  const int m0 = blockIdx.x * 128, n0 = blockIdx.y * 128;
  f32x4 acck[4][2] = {}, accv[4][2] = {};

  auto stage = [&](int buf, int k0) {
    size_t roff = (size_t)(tid >> 2) * K + k0 + (tid & 3) * 8;
    size_t loff = (size_t)tid * 8;
    gll16(A + (size_t)m0 * K + roff, &sm[buf][0] + loff);
    gll16(Wk + (size_t)n0 * K + roff, &sm[buf][4096] + loff);
    gll16(Wv + (size_t)n0 * K + roff, &sm[buf][8192] + loff);
  };

  stage(0, 0);
  __syncthreads();
  for (int t = 0; t < 32; ++t) {
    if (t < 31) stage((t + 1) & 1, (t + 1) * 32);
    const unsigned short* lA = &sm[t & 1][0];
    const unsigned short* lBk = &sm[t & 1][4096];
    const unsigned short* lBv = &sm[t & 1][8192];
    s16x8 af[4], bfk[2], bfv[2];
#pragma unroll
    for (int mi = 0; mi < 4; ++mi) af[mi] = *(const s16x8*)&lA[(wm * 64 + mi * 16 + lo) * 32 + hi * 8];
#pragma unroll
    for (int ni = 0; ni < 2; ++ni) {
      bfk[ni] = *(const s16x8*)&lBk[(wn * 32 + ni * 16 + lo) * 32 + hi * 8];
      bfv[ni] = *(const s16x8*)&lBv[(wn * 32 + ni * 16 + lo) * 32 + hi * 8];
    }
#pragma unroll
    for (int mi = 0; mi < 4; ++mi)
#pragma unroll
      for (int ni = 0; ni < 2; ++ni) {
        acck[mi][ni] = __builtin_amdgcn_mfma_f32_16x16x32_bf16(af[mi], bfk[ni], acck[mi][ni], 0, 0, 0);
        accv[mi][ni] = __builtin_amdgcn_mfma_f32_16x16x32_bf16(af[mi], bfv[ni], accv[mi][ni], 0, 0, 0);
      }
    __syncthreads();
  }

  // K epilogue: direct global stores
#pragma unroll
  for (int mi = 0; mi < 4; ++mi)
#pragma unroll
    for (int ni = 0; ni < 2; ++ni)
#pragma unroll
      for (int j = 0; j < 4; ++j) {
        int m = m0 + wm * 64 + mi * 16 + hi * 4 + j;
        int n = n0 + wn * 32 + ni * 16 + lo;
        int b = m >> 11, s = m & 2047, hh = n >> 6, e = n & 63;
        kws[((size_t)(b * NHn + hh) * Sseq + s) * HSn + e] = f2bf(acck[mi][ni][j]);
      }
  // V epilogue: LDS transpose (reuses sm flat: needs 17408 shorts < 24576)
  unsigned short* tp = &sm[0][0];
  __syncthreads();
#pragma unroll
  for (int mi = 0; mi < 4; ++mi)
#pragma unroll
    for (int ni = 0; ni < 2; ++ni)
#pragma unroll
      for (int j = 0; j < 4; ++j) {
        int ml = wm * 64 + mi * 16 + hi * 4 + j;
        int nl = wn * 32 + ni * 16 + lo;
        tp[(size_t)nl * 136 + ml] = f2bf(accv[mi][ni][j]);
      }
  __syncthreads();
  int nl = tid >> 2, seg = tid & 3;
  int b = m0 >> 11, hh = (n0 + nl) >> 6, e = (n0 + nl) & 63;
  unsigned short* dst = vtw + ((size_t)(b * NHn + hh) * HSn + e) * Sseq + (m0 & 2047) + seg * 32;
#pragma unroll
  for (int i = 0; i < 4; ++i)
    *(s16x8*)(dst + i * 8) = *(const s16x8*)&tp[(size_t)nl * 136 + seg * 32 + i * 8];
}

// ------ final projection GEMM: BK=64, 8 waves (2x4), fp32 out [M][1024] + bias -------
__global__ __launch_bounds__(512, 4) void gemm_p(const unsigned short* __restrict__ A,
                                                 const unsigned short* __restrict__ W,
                                                 float* __restrict__ outf,
                                                 const float* __restrict__ bias) {
  constexpr int K = 1024;
  __shared__ unsigned short sm[2][16384];
  const int tid = threadIdx.x;
  const int w = tid >> 6, lane = tid & 63, lo = lane & 15, hi = lane >> 4;
  const int wm = w >> 2, wn = w & 3;
  const int m0 = blockIdx.x * 128, n0 = blockIdx.y * 128;
  f32x4 acc[4][2] = {};

  auto stage = [&](int buf, int k0) {
#pragma unroll
    for (int h = 0; h < 2; ++h) {
      int c = h * 512 + tid;
      int r = c >> 3, sg = (c & 7) ^ (r & 7);
      gll16(A + (size_t)(m0 + r) * K + k0 + sg * 8, &sm[buf][0] + (size_t)c * 8);
      gll16(W + (size_t)(n0 + r) * K + k0 + sg * 8, &sm[buf][8192] + (size_t)c * 8);
    }
  };

  stage(0, 0);
  __syncthreads();
  for (int t = 0; t < 16; ++t) {
    if (t < 15) stage((t + 1) & 1, (t + 1) * 64);
    const unsigned short* lA = &sm[t & 1][0];
    const unsigned short* lB = &sm[t & 1][8192];
    s16x8 af[4][2], bfr[2][2];
#pragma unroll
    for (int mi = 0; mi < 4; ++mi) {
      int r = wm * 64 + mi * 16 + lo;
#pragma unroll
      for (int kk = 0; kk < 2; ++kk)
        af[mi][kk] = *(const s16x8*)&lA[r * 64 + ((kk * 32 + hi * 8) ^ ((r & 7) << 3))];
    }
#pragma unroll
    for (int ni = 0; ni < 2; ++ni) {
      int r = wn * 32 + ni * 16 + lo;
#pragma unroll
      for (int kk = 0; kk < 2; ++kk)
        bfr[ni][kk] = *(const s16x8*)&lB[r * 64 + ((kk * 32 + hi * 8) ^ ((r & 7) << 3))];
    }
#pragma unroll
    for (int mi = 0; mi < 4; ++mi)
#pragma unroll
      for (int ni = 0; ni < 2; ++ni)
#pragma unroll
        for (int kk = 0; kk < 2; ++kk)
          acc[mi][ni] = __builtin_amdgcn_mfma_f32_16x16x32_bf16(af[mi][kk], bfr[ni][kk], acc[mi][ni], 0, 0, 0);
    __syncthreads();
  }
  float bv[2];
#pragma unroll
  for (int ni = 0; ni < 2; ++ni) bv[ni] = bias[n0 + wn * 32 + ni * 16 + lo];
#pragma unroll
  for (int mi = 0; mi < 4; ++mi)
#pragma unroll
    for (int ni = 0; ni < 2; ++ni)
#pragma unroll
      for (int j = 0; j < 4; ++j) {
        int m = m0 + wm * 64 + mi * 16 + hi * 4 + j;
        int n = n0 + wn * 32 + ni * 16 + lo;
        outf[(size_t)m * 1024 + n] = acc[mi][ni][j] + bv[ni];
      }
}

// ---------------- flash attention (R16-verified: 8-wave, permuted-K, in-reg P) --------
// K rows staged bit-permuted: storage row s holds logical ((s&0x1C)<<1)|((s&0x20)>>3)|(s&3).
// QK^T slot (t,hi,j) = logical kpos 32(t&1)+8hi+4(t>>1)+j; PV B-fragment is a pure
// register rearrangement of packed P (zero-LDS P path). Defer-max (thr=11, exp2 domain)
// + l via ones-MFMA. setprio(1) wraps MFMA clusters.
DEV void attn_unit16(const unsigned short* __restrict__ kbc,
                     const unsigned short* __restrict__ vbc,
                     const s16x8 (&qf)[2], f32x4 (&oacc)[4], f32x4& lacc,
                     float& mrun, const s16x8& ones,
                     int k0, int qw0, int lo, int hi, int b,
                     const int* __restrict__ pad, const int* __restrict__ tmask,
                     bool trivial) {
  if (k0 > qw0 + 15) return; // wave-uniform: tile entirely above this wave's rows

  // S^T = K Q^T (operand-swapped; K rows permuted in LDS)
  f32x4 st[4];
  __builtin_amdgcn_s_setprio(1);
#pragma unroll
  for (int t = 0; t < 4; ++t) {
    f32x4 z = {0.f, 0.f, 0.f, 0.f};
#pragma unroll
    for (int kk = 0; kk < 2; ++kk) {
      s16x8 kfr = *(const s16x8*)&kbc[(t * 16 + lo) * 72 + kk * 32 + hi * 8];
      z = __builtin_amdgcn_mfma_f32_16x16x32_bf16(kfr, qf[kk], z, 0, 0, 0);
    }
    st[t] = z;
  }
  __builtin_amdgcn_s_setprio(0);
  const int qg = qw0 + lo;
  const int kgb = k0 + hi * 8; // logical kpos base for this lane's slots
  if (k0 + 63 > qw0) { // diagonal tiles: causal mask (logical kpos > q)
#pragma unroll
    for (int t = 0; t < 4; ++t)
#pragma unroll
      for (int j = 0; j < 4; ++j) {
        int kg = kgb + ((t & 1) << 5) + ((t >> 1) << 2) + j;
        if (kg > qg) st[t][j] = -3e38f;
      }
  }
  if (!trivial) { // general pad/time masks (not hit for all-ones inputs)
#pragma unroll
    for (int t = 0; t < 4; ++t)
#pragma unroll
      for (int j = 0; j < 4; ++j) {
        int kg = kgb + ((t & 1) << 5) + ((t >> 1) << 2) + j;
        if (!pad[b * Sseq + kg] || !tmask[(size_t)qg * Sseq + kg]) st[t][j] = -3e38f;
      }
  }
  // tile max for this lane's q-column (lane-local + 2 shuffles over hi-groups)
  float m0v = fmaxf(fmaxf(st[0][0], st[0][1]), fmaxf(st[0][2], st[0][3]));
  float m1v = fmaxf(fmaxf(st[1][0], st[1][1]), fmaxf(st[1][2], st[1][3]));
  float m2v = fmaxf(fmaxf(st[2][0], st[2][1]), fmaxf(st[2][2], st[2][3]));
  float m3v = fmaxf(fmaxf(st[3][0], st[3][1]), fmaxf(st[3][2], st[3][3]));
  float mx = fmaxf(fmaxf(m0v, m1v), fmaxf(m2v, m3v));
  mx = fmaxf(mx, __shfl_xor(mx, 16, 64));
  mx = fmaxf(mx, __shfl_xor(mx, 32, 64));
  // defer-max: only rescale when the bound would be exceeded (P <= 2^11 otherwise)
  if (!__all(mx <= mrun + 11.f)) {
    const float mnew = fmaxf(mrun, mx);
    const float al = __builtin_amdgcn_exp2f(mrun - mnew);
    mrun = mnew;
#pragma unroll
    for (int et = 0; et < 4; ++et) oacc[et] *= al;
    lacc *= al;
  }
  // P = exp2(S - mrun), packed to bf16 pairs in registers
  unsigned int pk[4][2];
#pragma unroll
  for (int t = 0; t < 4; ++t) {
    float p0 = __builtin_amdgcn_exp2f(st[t][0] - mrun);
    float p1 = __builtin_amdgcn_exp2f(st[t][1] - mrun);
    float p2 = __builtin_amdgcn_exp2f(st[t][2] - mrun);
    float p3 = __builtin_amdgcn_exp2f(st[t][3] - mrun);
    pk[t][0] = cvtpk(p0, p1);
    pk[t][1] = cvtpk(p2, p3);
  }
  // assemble PV B-fragments in registers (kpos = kk*32 + hi*8 + 0..7, col q = lo)
  U8 pf0, pf1;
  pf0.u[0] = pk[0][0]; pf0.u[1] = pk[0][1]; pf0.u[2] = pk[2][0]; pf0.u[3] = pk[2][1];
  pf1.u[0] = pk[1][0]; pf1.u[1] = pk[1][1]; pf1.u[2] = pk[3][0]; pf1.u[3] = pk[3][1];
  // O^T += V^T P^T ; l += ones . P (all rows of lacc equal l[q])
  __builtin_amdgcn_s_setprio(1);
#pragma unroll
  for (int et = 0; et < 4; ++et) {
    s16x8 vf0 = *(const s16x8*)&vbc[(et * 16 + lo) * 72 + hi * 8];
    s16x8 vf1 = *(const s16x8*)&vbc[(et * 16 + lo) * 72 + 32 + hi * 8];
    oacc[et] = __builtin_amdgcn_mfma_f32_16x16x32_bf16(vf0, pf0.v, oacc[et], 0, 0, 0);
    oacc[et] = __builtin_amdgcn_mfma_f32_16x16x32_bf16(vf1, pf1.v, oacc[et], 0, 0, 0);
  }
  lacc = __builtin_amdgcn_mfma_f32_16x16x32_bf16(ones, pf0.v, lacc, 0, 0, 0);
  lacc = __builtin_amdgcn_mfma_f32_16x16x32_bf16(ones, pf1.v, lacc, 0, 0, 0);
  __builtin_amdgcn_s_setprio(0);
}

// normalize by l (lane-local) and write O via per-wave LDS transpose (16 rows)
DEV void attn_epi16(f32x4 (&oacc)[4], float lrun,
                    unsigned short* __restrict__ scr,
                    unsigned short* __restrict__ O, int b, int hh, int qw0,
                    int lane, int lo, int hi) {
  const float inv = 1.f / lrun;
#pragma unroll
  for (int et = 0; et < 4; ++et) {
    f32x4 o = oacc[et] * inv;
    u32x2 d = {cvtpk(o[0], o[1]), cvtpk(o[2], o[3])};
    *(u32x2*)&scr[lo * 72 + et * 16 + hi * 4] = d;
  }
  int q = lane >> 2, seg = lane & 3;
  unsigned short* dst = O + ((size_t)b * Sseq + qw0 + q) * Dm + hh * HSn + seg * 16;
  *(s16x8*)dst = *(const s16x8*)&scr[q * 72 + seg * 16];
  *(s16x8*)(dst + 8) = *(const s16x8*)&scr[q * 72 + seg * 16 + 8];
}

__global__ __launch_bounds__(512, 4) void attn_kernel(const unsigned short* __restrict__ Q,
                                                      const unsigned short* __restrict__ Kg,
                                                      const unsigned short* __restrict__ Vt,
                                                      unsigned short* __restrict__ O,
                                                      const int* __restrict__ pad,
                                                      const int* __restrict__ tmask,
                                                      const int* __restrict__ flags) {
  __shared__ unsigned short kb[2][64 * 72];   // 18.0 KiB (epilogue reuses as scratch)
  __shared__ unsigned short vb[2][64 * 72];   // 18.0 KiB

  const int ip = blockIdx.y, bh = blockIdx.x; // bh fastest -> same-bh blocks on one XCD
  const int b = bh >> 4, hh = bh & 15;
  const int tid = threadIdx.x, w = tid >> 6, lane = tid & 63, lo = lane & 15, hi = lane >> 4;
  const int qtA = ip, qtB = 15 - ip;
  const int qw0A = qtA * 128 + w * 16, qw0B = qtB * 128 + w * 16;
  const int ktA = 2 * qtA + 1;       // last K-tile index tile A needs (any wave)
  const int ktmax = 2 * qtB + 2;     // number of K-tiles tile B needs
  const bool trivial = flags[0] == 0;

  const unsigned short* Qb = Q + (size_t)bh * Sseq * HSn;
  const unsigned short* Kb = Kg + (size_t)bh * Sseq * HSn;
  const unsigned short* Vb = Vt + (size_t)bh * HSn * Sseq;

  // Q fragments (B-operand of swapped QK^T)
  s16x8 qfA[2], qfB[2];
#pragma unroll
  for (int kk = 0; kk < 2; ++kk) {
    qfA[kk] = *(const s16x8*)&Qb[(size_t)(qw0A + lo) * HSn + kk * 32 + hi * 8];
    qfB[kk] = *(const s16x8*)&Qb[(size_t)(qw0B + lo) * HSn + kk * 32 + hi * 8];
  }

  s16x8 ones;
#pragma unroll
  for (int j = 0; j < 8; ++j) ones[j] = (short)0x3F80; // bf16 1.0

  f32x4 oaccA[4] = {}, oaccB[4] = {};
  f32x4 laccA = {}, laccB = {};
  float mrunA = -3e38f, mrunB = -3e38f;

  // staging: waves 0-3 handle K (bit-permuted row order), waves 4-7 handle V
  const int shalf = tid >> 8, st_t = tid & 255;
  const int sr = st_t >> 2, sc = (st_t & 3) * 16;
  // logical K row for storage row sr: L = [s4 s3 s2 | s5 | s1 s0]
  const int srK = ((sr & 0x1C) << 1) | ((sr & 0x20) >> 3) | (sr & 3);

  // prologue: stage kt=0 into buffer 0
  s16x8 r0, r1;
  if (shalf == 0) {
    const unsigned short* gk = Kb + (size_t)srK * HSn + sc;
    r0 = *(const s16x8*)gk; r1 = *(const s16x8*)(gk + 8);
    *(s16x8*)&kb[0][sr * 72 + sc] = r0; *(s16x8*)&kb[0][sr * 72 + sc + 8] = r1;
  } else {
    const unsigned short* gv = Vb + (size_t)sr * Sseq + sc;
    r0 = *(const s16x8*)gv; r1 = *(const s16x8*)(gv + 8);
    *(s16x8*)&vb[0][sr * 72 + sc] = r0; *(s16x8*)&vb[0][sr * 72 + sc + 8] = r1;
  }
  __syncthreads();

  for (int kt = 0; kt < ktmax; ++kt) {
    const int cur = kt & 1, k0 = kt * 64;
    const bool pre = (kt + 1 < ktmax);
    if (pre) { // issue next-tile loads early; latency hides under compute
      const int k1 = k0 + 64;
      if (shalf == 0) {
        const unsigned short* gk = Kb + (size_t)(k1 + srK) * HSn + sc;
        r0 = *(const s16x8*)gk; r1 = *(const s16x8*)(gk + 8);
      } else {
        const unsigned short* gv = Vb + (size_t)sr * Sseq + k1 + sc;
        r0 = *(const s16x8*)gv; r1 = *(const s16x8*)(gv + 8);
      }
    }
    const unsigned short* kbc = kb[cur];
    const unsigned short* vbc = vb[cur];
    if (kt <= ktA)
      attn_unit16(kbc, vbc, qfA, oaccA, laccA, mrunA, ones,
                  k0, qw0A, lo, hi, b, pad, tmask, trivial);
    attn_unit16(kbc, vbc, qfB, oaccB, laccB, mrunB, ones,
                k0, qw0B, lo, hi, b, pad, tmask, trivial);
    if (pre) { // write-late into the other buffer
      const int nb = cur ^ 1;
      if (shalf == 0) {
        *(s16x8*)&kb[nb][sr * 72 + sc] = r0; *(s16x8*)&kb[nb][sr * 72 + sc + 8] = r1;
      } else {
        *(s16x8*)&vb[nb][sr * 72 + sc] = r0; *(s16x8*)&vb[nb][sr * 72 + sc + 8] = r1;
      }
    }
    __syncthreads();
  }

  // epilogue: per-wave scratch carved out of kb (all compute on kb finished above)
  unsigned short* scr = (unsigned short*)kb + (size_t)w * 1152;
  attn_epi16(oaccA, laccA[0], scr, O, b, hh, qw0A, lane, lo, hi);
  attn_epi16(oaccB, laccB[0], scr, O, b, hh, qw0B, lane, lo, hi);
}

extern "C" void kernel_launch(void* const* d_in, const int* in_sizes, int n_in,
                              void* d_out, int out_size, void* d_ws, size_t ws_size,
                              hipStream_t stream) {
  const float* x = (const float*)d_in[0];
  const float* y = (const float*)d_in[1];
  const int* pad = (const int*)d_in[2];
  const int* tmask = (const int*)d_in[3];
  const float* Wq = (const float*)d_in[4];
  const float* Wk = (const float*)d_in[5];
  const float* Wv = (const float*)d_in[6];
  const float* Wp = (const float*)d_in[7];
  const float* bp = (const float*)d_in[8];

  char* ws = (char*)d_ws;
  unsigned short* xbf = (unsigned short*)(ws + OFF_XBF);
  unsigned short* ybf = (unsigned short*)(ws + OFF_YBF);
  unsigned short* wqb = (unsigned short*)(ws + OFF_WQ);
  unsigned short* wkb = (unsigned short*)(ws + OFF_WK);
  unsigned short* wvb = (unsigned short*)(ws + OFF_WV);
  unsigned short* wpb = (unsigned short*)(ws + OFF_WP);
  unsigned short* qws = (unsigned short*)(ws + OFF_QWS);
  unsigned short* kws = (unsigned short*)(ws + OFF_KWS);
  unsigned short* vtw = (unsigned short*)(ws + OFF_VTWS);
  unsigned short* ows = (unsigned short*)(ws + OFF_OWS);
  int* flags = (int*)(ws + OFF_FLAG);

  hipMemsetAsync(flags, 0, 4, stream);
  cvt_all<<<12296, 256, 0, stream>>>(x, y, Wq, Wk, Wv, Wp, pad, tmask, ws, flags);

  q_gemm<<<dim3(64, 8), 512, 0, stream>>>(ybf, wqb, qws);
  kv_gemm<<<dim3(64, 8), 512, 0, stream>>>(xbf, wkb, wvb, kws, vtw);

  attn_kernel<<<dim3(64, 8), 512, 0, stream>>>(qws, kws, vtw, ows, pad, tmask, flags);

  gemm_p<<<dim3(64, 8), 512, 0, stream>>>(ows, wpb, (float*)d_out, bp);
}

// Round 20
// 171.461 us; speedup vs baseline: 1.0845x; 1.0217x over previous
//
#include <hip/hip_runtime.h>
#include <hip/hip_bf16.h>
#include <stdint.h>
#include <stddef.h>

// MultiHA: y@Wq^T -> q; x@Wk^T -> k; x@Wv^T -> v; causal softmax attn; @Wp^T + bp
// B=4 S=2048 D=1024 NH=16 HS=64. All GEMM/attn compute in bf16 MFMA, f32 accum.

typedef __attribute__((ext_vector_type(4))) float f32x4;
typedef __attribute__((ext_vector_type(8))) short s16x8;
typedef __attribute__((ext_vector_type(4))) float float4v;
typedef __attribute__((ext_vector_type(4))) int i32x4;
typedef __attribute__((ext_vector_type(2))) unsigned int u32x2;

#define DEV __device__ __forceinline__

constexpr int Bsz = 4, Sseq = 2048, Dm = 1024, NHn = 16, HSn = 64;
// fold 1/sqrt(HS) * log2(e) into Wq so attention softmax runs in exp2 domain
constexpr float QSCALE = 0.125f * 1.4426950408889634f;

// ---- workspace layout (bytes) ----
constexpr size_t SZ_BF_XY = (size_t)Bsz * Sseq * Dm * 2;  // 16 MiB
constexpr size_t SZ_W     = (size_t)Dm * Dm * 2;          // 2 MiB
constexpr size_t OFF_XBF  = 0;
constexpr size_t OFF_YBF  = OFF_XBF + SZ_BF_XY;
constexpr size_t OFF_WQ   = OFF_YBF + SZ_BF_XY;
constexpr size_t OFF_WK   = OFF_WQ + SZ_W;
constexpr size_t OFF_WV   = OFF_WK + SZ_W;
constexpr size_t OFF_WP   = OFF_WV + SZ_W;
constexpr size_t OFF_QWS  = OFF_WP + SZ_W;   // [BH][S][64] bf16
constexpr size_t OFF_KWS  = OFF_QWS + SZ_BF_XY;
constexpr size_t OFF_VTWS = OFF_KWS + SZ_BF_XY; // [BH][64][S] bf16 (V transposed)
constexpr size_t OFF_OWS  = OFF_VTWS + SZ_BF_XY; // attn out [B][S][D] bf16
constexpr size_t OFF_FLAG = OFF_OWS + SZ_BF_XY;

DEV unsigned short f2bf(float f) {
  union { float f; unsigned int u; } v; v.f = f;
  unsigned int r = (v.u + 0x7FFFu + ((v.u >> 16) & 1u)) >> 16;
  return (unsigned short)r;
}

DEV void gll16(const void* g, void* l) {
  __builtin_amdgcn_global_load_lds((const __attribute__((address_space(1))) unsigned int*)g,
                                   (__attribute__((address_space(3))) unsigned int*)l, 16, 0, 0);
}

DEV unsigned int cvtpk(float a, float b) {
  unsigned int r;
  asm("v_cvt_pk_bf16_f32 %0, %1, %2" : "=v"(r) : "v"(a), "v"(b));
  return r;
}

union U8 { s16x8 v; unsigned int u[4]; };

// ------ fused fp32->bf16 conversion of all inputs + pad/tmask triviality check ------
__global__ void cvt_all(const float* __restrict__ x, const float* __restrict__ y,
                        const float* __restrict__ Wq, const float* __restrict__ Wk,
                        const float* __restrict__ Wv, const float* __restrict__ Wp,
                        const int* __restrict__ pad, const int* __restrict__ tmask,
                        char* __restrict__ ws, int* __restrict__ flags) {
  const int blk = blockIdx.x;
  if (blk >= 10240) {
    int bad = 0;
    if (blk < 10248) { // pad: 8192 ints, 4 per thread
      const i32x4 v = ((const i32x4*)pad)[(blk - 10240) * 256 + threadIdx.x];
      bad = (v[0] == 0) | (v[1] == 0) | (v[2] == 0) | (v[3] == 0);
    } else { // tmask: 4M ints, 8 per thread
      const i32x4* tp = (const i32x4*)tmask + ((size_t)(blk - 10248) * 256 + threadIdx.x) * 2;
      i32x4 v0 = tp[0], v1 = tp[1];
      bad = (v0[0] == 0) | (v0[1] == 0) | (v0[2] == 0) | (v0[3] == 0) |
            (v1[0] == 0) | (v1[1] == 0) | (v1[2] == 0) | (v1[3] == 0);
    }
    if (__builtin_amdgcn_ballot_w64(bad) != 0 && (threadIdx.x & 63) == 0)
      atomicOr(flags, 1);
    return;
  }
  const float* src;
  unsigned short* dst;
  int b8;
  float scale = 1.f;
  if (blk < 4096)      { src = x;  dst = (unsigned short*)(ws + OFF_XBF); b8 = blk; }
  else if (blk < 8192) { src = y;  dst = (unsigned short*)(ws + OFF_YBF); b8 = blk - 4096; }
  else if (blk < 8704) { src = Wq; dst = (unsigned short*)(ws + OFF_WQ);  b8 = blk - 8192; scale = QSCALE; }
  else if (blk < 9216) { src = Wk; dst = (unsigned short*)(ws + OFF_WK);  b8 = blk - 8704; }
  else if (blk < 9728) { src = Wv; dst = (unsigned short*)(ws + OFF_WV);  b8 = blk - 9216; }
  else                 { src = Wp; dst = (unsigned short*)(ws + OFF_WP);  b8 = blk - 9728; }
  const size_t i = (size_t)b8 * 256 + threadIdx.x;
  const float4v* s = (const float4v*)src + i * 2;
  float4v a = s[0], b = s[1];
  s16x8 o;
  o[0] = (short)f2bf(a[0] * scale); o[1] = (short)f2bf(a[1] * scale);
  o[2] = (short)f2bf(a[2] * scale); o[3] = (short)f2bf(a[3] * scale);
  o[4] = (short)f2bf(b[0] * scale); o[5] = (short)f2bf(b[1] * scale);
  o[6] = (short)f2bf(b[2] * scale); o[7] = (short)f2bf(b[3] * scale);
  *(s16x8*)(dst + i * 8) = o;
}

// ------ merged Q + KV projection GEMM, z-routed --------------------------------------
// z=0: Q path (BK=64, T2-swizzled, verified R19 q_gemm).
// z=1: KV path (BK=32, shared-A staging, verified R19 kv_gemm).
// LDS = union (64 KiB); both paths' layouts verified independently.
__global__ __launch_bounds__(512, 4) void qkv_gemm(const unsigned short* __restrict__ xbf,
                                                   const unsigned short* __restrict__ ybf,
                                                   const unsigned short* __restrict__ wqb,
                                                   const unsigned short* __restrict__ wkb,
                                                   const unsigned short* __restrict__ wvb,
                                                   unsigned short* __restrict__ qws,
                                                   unsigned short* __restrict__ kws,
                                                   unsigned short* __restrict__ vtw) {
  constexpr int K = 1024;
  __shared__ unsigned short sm[2][16384]; // 64 KiB union
  const int tid = threadIdx.x;
  const int w = tid >> 6, lane = tid & 63, lo = lane & 15, hi = lane >> 4;
  const int wm = w >> 2, wn = w & 3;
  const int m0 = blockIdx.x * 128, n0 = blockIdx.y * 128;

  if (blockIdx.z == 0) {
    // ---- Q path: BK=64, swizzled (global source pre-swizzled seg^=(row&7)) ----
    const unsigned short* A = ybf;
    const unsigned short* W = wqb;
    f32x4 acc[4][2] = {};
    auto stage = [&](int buf, int k0) {
#pragma unroll
      for (int h = 0; h < 2; ++h) {
        int c = h * 512 + tid;
        int r = c >> 3, sg = (c & 7) ^ (r & 7);
        gll16(A + (size_t)(m0 + r) * K + k0 + sg * 8, &sm[buf][0] + (size_t)c * 8);
        gll16(W + (size_t)(n0 + r) * K + k0 + sg * 8, &sm[buf][8192] + (size_t)c * 8);
      }
    };
    stage(0, 0);
    __syncthreads();
    for (int t = 0; t < 16; ++t) {
      if (t < 15) stage((t + 1) & 1, (t + 1) * 64);
      const unsigned short* lA = &sm[t & 1][0];
      const unsigned short* lB = &sm[t & 1][8192];
      s16x8 af[4][2], bfr[2][2];
#pragma unroll
      for (int mi = 0; mi < 4; ++mi) {
        int r = wm * 64 + mi * 16 + lo;
#pragma unroll
        for (int kk = 0; kk < 2; ++kk)
          af[mi][kk] = *(const s16x8*)&lA[r * 64 + ((kk * 32 + hi * 8) ^ ((r & 7) << 3))];
      }
#pragma unroll
      for (int ni = 0; ni < 2; ++ni) {
        int r = wn * 32 + ni * 16 + lo;
#pragma unroll
        for (int kk = 0; kk < 2; ++kk)
          bfr[ni][kk] = *(const s16x8*)&lB[r * 64 + ((kk * 32 + hi * 8) ^ ((r & 7) << 3))];
      }
#pragma unroll
      for (int mi = 0; mi < 4; ++mi)
#pragma unroll
        for (int ni = 0; ni < 2; ++ni)
#pragma unroll
          for (int kk = 0; kk < 2; ++kk)
            acc[mi][ni] = __builtin_amdgcn_mfma_f32_16x16x32_bf16(af[mi][kk], bfr[ni][kk], acc[mi][ni], 0, 0, 0);
      __syncthreads();
    }
#pragma unroll
    for (int mi = 0; mi < 4; ++mi)
#pragma unroll
      for (int ni = 0; ni < 2; ++ni)
#pragma unroll
        for (int j = 0; j < 4; ++j) {
          int m = m0 + wm * 64 + mi * 16 + hi * 4 + j;
          int n = n0 + wn * 32 + ni * 16 + lo;
          int b = m >> 11, s = m & 2047, hh = n >> 6, e = n & 63;
          qws[((size_t)(b * NHn + hh) * Sseq + s) * HSn + e] = f2bf(acc[mi][ni][j]);
        }
  } else {
    // ---- KV path: BK=32, shared-A staging, two accumulators ----
    const unsigned short* A = xbf;
    f32x4 acck[4][2] = {}, accv[4][2] = {};
    auto stage = [&](int buf, int k0) {
      size_t roff = (size_t)(tid >> 2) * K + k0 + (tid & 3) * 8;
      size_t loff = (size_t)tid * 8;
      gll16(A + (size_t)m0 * K + roff, &sm[buf][0] + loff);
      gll16(wkb + (size_t)n0 * K + roff, &sm[buf][4096] + loff);
      gll16(wvb + (size_t)n0 * K + roff, &sm[buf][8192] + loff);
    };
    stage(0, 0);
    __syncthreads();
    for (int t = 0; t < 32; ++t) {
      if (t < 31) stage((t + 1) & 1, (t + 1) * 32);
      const unsigned short* lA = &sm[t & 1][0];
      const unsigned short* lBk = &sm[t & 1][4096];
      const unsigned short* lBv = &sm[t & 1][8192];
      s16x8 af[4], bfk[2], bfv[2];
#pragma unroll
      for (int mi = 0; mi < 4; ++mi) af[mi] = *(const s16x8*)&lA[(wm * 64 + mi * 16 + lo) * 32 + hi * 8];
#pragma unroll
      for (int ni = 0; ni < 2; ++ni) {
        bfk[ni] = *(const s16x8*)&lBk[(wn * 32 + ni * 16 + lo) * 32 + hi * 8];
        bfv[ni] = *(const s16x8*)&lBv[(wn * 32 + ni * 16 + lo) * 32 + hi * 8];
      }
#pragma unroll
      for (int mi = 0; mi < 4; ++mi)
#pragma unroll
        for (int ni = 0; ni < 2; ++ni) {
          acck[mi][ni] = __builtin_amdgcn_mfma_f32_16x16x32_bf16(af[mi], bfk[ni], acck[mi][ni], 0, 0, 0);
          accv[mi][ni] = __builtin_amdgcn_mfma_f32_16x16x32_bf16(af[mi], bfv[ni], accv[mi][ni], 0, 0, 0);
        }
      __syncthreads();
    }
    // K epilogue: direct global stores
#pragma unroll
    for (int mi = 0; mi < 4; ++mi)
#pragma unroll
      for (int ni = 0; ni < 2; ++ni)
#pragma unroll
        for (int j = 0; j < 4; ++j) {
          int m = m0 + wm * 64 + mi * 16 + hi * 4 + j;
          int n = n0 + wn * 32 + ni * 16 + lo;
          int b = m >> 11, s = m & 2047, hh = n >> 6, e = n & 63;
          kws[((size_t)(b * NHn + hh) * Sseq + s) * HSn + e] = f2bf(acck[mi][ni][j]);
        }
    // V epilogue: LDS transpose (reuses sm flat: 17408 shorts < 32768)
    unsigned short* tp = &sm[0][0];
    __syncthreads();
#pragma unroll
    for (int mi = 0; mi < 4; ++mi)
#pragma unroll
      for (int ni = 0; ni < 2; ++ni)
#pragma unroll
        for (int j = 0; j < 4; ++j) {
          int ml = wm * 64 + mi * 16 + hi * 4 + j;
          int nl = wn * 32 + ni * 16 + lo;
          tp[(size_t)nl * 136 + ml] = f2bf(accv[mi][ni][j]);
        }
    __syncthreads();
    int nl = tid >> 2, seg = tid & 3;
    int b = m0 >> 11, hh = (n0 + nl) >> 6, e = (n0 + nl) & 63;
    unsigned short* dst = vtw + ((size_t)(b * NHn + hh) * HSn + e) * Sseq + (m0 & 2047) + seg * 32;
#pragma unroll
    for (int i = 0; i < 4; ++i)
      *(s16x8*)(dst + i * 8) = *(const s16x8*)&tp[(size_t)nl * 136 + seg * 32 + i * 8];
  }
}

// ------ final projection GEMM: BK=64, 8 waves (2x4), fp32 out [M][1024] + bias -------
__global__ __launch_bounds__(512, 4) void gemm_p(const unsigned short* __restrict__ A,
                                                 const unsigned short* __restrict__ W,
                                                 float* __restrict__ outf,
                                                 const float* __restrict__ bias) {
  constexpr int K = 1024;
  __shared__ unsigned short sm[2][16384];
  const int tid = threadIdx.x;
  const int w = tid >> 6, lane = tid & 63, lo = lane & 15, hi = lane >> 4;
  const int wm = w >> 2, wn = w & 3;
  const int m0 = blockIdx.x * 128, n0 = blockIdx.y * 128;
  f32x4 acc[4][2] = {};

  auto stage = [&](int buf, int k0) {
#pragma unroll
    for (int h = 0; h < 2; ++h) {
      int c = h * 512 + tid;
      int r = c >> 3, sg = (c & 7) ^ (r & 7);
      gll16(A + (size_t)(m0 + r) * K + k0 + sg * 8, &sm[buf][0] + (size_t)c * 8);
      gll16(W + (size_t)(n0 + r) * K + k0 + sg * 8, &sm[buf][8192] + (size_t)c * 8);
    }
  };

  stage(0, 0);
  __syncthreads();
  for (int t = 0; t < 16; ++t) {
    if (t < 15) stage((t + 1) & 1, (t + 1) * 64);
    const unsigned short* lA = &sm[t & 1][0];
    const unsigned short* lB = &sm[t & 1][8192];
    s16x8 af[4][2], bfr[2][2];
#pragma unroll
    for (int mi = 0; mi < 4; ++mi) {
      int r = wm * 64 + mi * 16 + lo;
#pragma unroll
      for (int kk = 0; kk < 2; ++kk)
        af[mi][kk] = *(const s16x8*)&lA[r * 64 + ((kk * 32 + hi * 8) ^ ((r & 7) << 3))];
    }
#pragma unroll
    for (int ni = 0; ni < 2; ++ni) {
      int r = wn * 32 + ni * 16 + lo;
#pragma unroll
      for (int kk = 0; kk < 2; ++kk)
        bfr[ni][kk] = *(const s16x8*)&lB[r * 64 + ((kk * 32 + hi * 8) ^ ((r & 7) << 3))];
    }
#pragma unroll
    for (int mi = 0; mi < 4; ++mi)
#pragma unroll
      for (int ni = 0; ni < 2; ++ni)
#pragma unroll
        for (int kk = 0; kk < 2; ++kk)
          acc[mi][ni] = __builtin_amdgcn_mfma_f32_16x16x32_bf16(af[mi][kk], bfr[ni][kk], acc[mi][ni], 0, 0, 0);
    __syncthreads();
  }
  float bv[2];
#pragma unroll
  for (int ni = 0; ni < 2; ++ni) bv[ni] = bias[n0 + wn * 32 + ni * 16 + lo];
#pragma unroll
  for (int mi = 0; mi < 4; ++mi)
#pragma unroll
    for (int ni = 0; ni < 2; ++ni)
#pragma unroll
      for (int j = 0; j < 4; ++j) {
        int m = m0 + wm * 64 + mi * 16 + hi * 4 + j;
        int n = n0 + wn * 32 + ni * 16 + lo;
        outf[(size_t)m * 1024 + n] = acc[mi][ni][j] + bv[ni];
      }
}

// ---------------- flash attention (R16-verified: 8-wave, permuted-K, in-reg P) --------
// K rows staged bit-permuted: storage row s holds logical ((s&0x1C)<<1)|((s&0x20)>>3)|(s&3).
// QK^T slot (t,hi,j) = logical kpos 32(t&1)+8hi+4(t>>1)+j; PV B-fragment is a pure
// register rearrangement of packed P (zero-LDS P path). Defer-max (thr=11, exp2 domain)
// + l via ones-MFMA. setprio(1) wraps MFMA clusters.
DEV void attn_unit16(const unsigned short* __restrict__ kbc,
                     const unsigned short* __restrict__ vbc,
                     const s16x8 (&qf)[2], f32x4 (&oacc)[4], f32x4& lacc,
                     float& mrun, const s16x8& ones,
                     int k0, int qw0, int lo, int hi, int b,
                     const int* __restrict__ pad, const int* __restrict__ tmask,
                     bool trivial) {
  if (k0 > qw0 + 15) return; // wave-uniform: tile entirely above this wave's rows

  // S^T = K Q^T (operand-swapped; K rows permuted in LDS)
  f32x4 st[4];
  __builtin_amdgcn_s_setprio(1);
#pragma unroll
  for (int t = 0; t < 4; ++t) {
    f32x4 z = {0.f, 0.f, 0.f, 0.f};
#pragma unroll
    for (int kk = 0; kk < 2; ++kk) {
      s16x8 kfr = *(const s16x8*)&kbc[(t * 16 + lo) * 72 + kk * 32 + hi * 8];
      z = __builtin_amdgcn_mfma_f32_16x16x32_bf16(kfr, qf[kk], z, 0, 0, 0);
    }
    st[t] = z;
  }
  __builtin_amdgcn_s_setprio(0);
  const int qg = qw0 + lo;
  const int kgb = k0 + hi * 8; // logical kpos base for this lane's slots
  if (k0 + 63 > qw0) { // diagonal tiles: causal mask (logical kpos > q)
#pragma unroll
    for (int t = 0; t < 4; ++t)
#pragma unroll
      for (int j = 0; j < 4; ++j) {
        int kg = kgb + ((t & 1) << 5) + ((t >> 1) << 2) + j;
        if (kg > qg) st[t][j] = -3e38f;
      }
  }
  if (!trivial) { // general pad/time masks (not hit for all-ones inputs)
#pragma unroll
    for (int t = 0; t < 4; ++t)
#pragma unroll
      for (int j = 0; j < 4; ++j) {
        int kg = kgb + ((t & 1) << 5) + ((t >> 1) << 2) + j;
        if (!pad[b * Sseq + kg] || !tmask[(size_t)qg * Sseq + kg]) st[t][j] = -3e38f;
      }
  }
  // tile max for this lane's q-column (lane-local + 2 shuffles over hi-groups)
  float m0v = fmaxf(fmaxf(st[0][0], st[0][1]), fmaxf(st[0][2], st[0][3]));
  float m1v = fmaxf(fmaxf(st[1][0], st[1][1]), fmaxf(st[1][2], st[1][3]));
  float m2v = fmaxf(fmaxf(st[2][0], st[2][1]), fmaxf(st[2][2], st[2][3]));
  float m3v = fmaxf(fmaxf(st[3][0], st[3][1]), fmaxf(st[3][2], st[3][3]));
  float mx = fmaxf(fmaxf(m0v, m1v), fmaxf(m2v, m3v));
  mx = fmaxf(mx, __shfl_xor(mx, 16, 64));
  mx = fmaxf(mx, __shfl_xor(mx, 32, 64));
  // defer-max: only rescale when the bound would be exceeded (P <= 2^11 otherwise)
  if (!__all(mx <= mrun + 11.f)) {
    const float mnew = fmaxf(mrun, mx);
    const float al = __builtin_amdgcn_exp2f(mrun - mnew);
    mrun = mnew;
#pragma unroll
    for (int et = 0; et < 4; ++et) oacc[et] *= al;
    lacc *= al;
  }
  // P = exp2(S - mrun), packed to bf16 pairs in registers
  unsigned int pk[4][2];
#pragma unroll
  for (int t = 0; t < 4; ++t) {
    float p0 = __builtin_amdgcn_exp2f(st[t][0] - mrun);
    float p1 = __builtin_amdgcn_exp2f(st[t][1] - mrun);
    float p2 = __builtin_amdgcn_exp2f(st[t][2] - mrun);
    float p3 = __builtin_amdgcn_exp2f(st[t][3] - mrun);
    pk[t][0] = cvtpk(p0, p1);
    pk[t][1] = cvtpk(p2, p3);
  }
  // assemble PV B-fragments in registers (kpos = kk*32 + hi*8 + 0..7, col q = lo)
  U8 pf0, pf1;
  pf0.u[0] = pk[0][0]; pf0.u[1] = pk[0][1]; pf0.u[2] = pk[2][0]; pf0.u[3] = pk[2][1];
  pf1.u[0] = pk[1][0]; pf1.u[1] = pk[1][1]; pf1.u[2] = pk[3][0]; pf1.u[3] = pk[3][1];
  // O^T += V^T P^T ; l += ones . P (all rows of lacc equal l[q])
  __builtin_amdgcn_s_setprio(1);
#pragma unroll
  for (int et = 0; et < 4; ++et) {
    s16x8 vf0 = *(const s16x8*)&vbc[(et * 16 + lo) * 72 + hi * 8];
    s16x8 vf1 = *(const s16x8*)&vbc[(et * 16 + lo) * 72 + 32 + hi * 8];
    oacc[et] = __builtin_amdgcn_mfma_f32_16x16x32_bf16(vf0, pf0.v, oacc[et], 0, 0, 0);
    oacc[et] = __builtin_amdgcn_mfma_f32_16x16x32_bf16(vf1, pf1.v, oacc[et], 0, 0, 0);
  }
  lacc = __builtin_amdgcn_mfma_f32_16x16x32_bf16(ones, pf0.v, lacc, 0, 0, 0);
  lacc = __builtin_amdgcn_mfma_f32_16x16x32_bf16(ones, pf1.v, lacc, 0, 0, 0);
  __builtin_amdgcn_s_setprio(0);
}

// normalize by l (lane-local) and write O via per-wave LDS transpose (16 rows)
DEV void attn_epi16(f32x4 (&oacc)[4], float lrun,
                    unsigned short* __restrict__ scr,
                    unsigned short* __restrict__ O, int b, int hh, int qw0,
                    int lane, int lo, int hi) {
  const float inv = 1.f / lrun;
#pragma unroll
  for (int et = 0; et < 4; ++et) {
    f32x4 o = oacc[et] * inv;
    u32x2 d = {cvtpk(o[0], o[1]), cvtpk(o[2], o[3])};
    *(u32x2*)&scr[lo * 72 + et * 16 + hi * 4] = d;
  }
  int q = lane >> 2, seg = lane & 3;
  unsigned short* dst = O + ((size_t)b * Sseq + qw0 + q) * Dm + hh * HSn + seg * 16;
  *(s16x8*)dst = *(const s16x8*)&scr[q * 72 + seg * 16];
  *(s16x8*)(dst + 8) = *(const s16x8*)&scr[q * 72 + seg * 16 + 8];
}

__global__ __launch_bounds__(512, 4) void attn_kernel(const unsigned short* __restrict__ Q,
                                                      const unsigned short* __restrict__ Kg,
                                                      const unsigned short* __restrict__ Vt,
                                                      unsigned short* __restrict__ O,
                                                      const int* __restrict__ pad,
                                                      const int* __restrict__ tmask,
                                                      const int* __restrict__ flags) {
  __shared__ unsigned short kb[2][64 * 72];   // 18.0 KiB (epilogue reuses as scratch)
  __shared__ unsigned short vb[2][64 * 72];   // 18.0 KiB

  const int ip = blockIdx.y, bh = blockIdx.x; // bh fastest -> same-bh blocks on one XCD
  const int b = bh >> 4, hh = bh & 15;
  const int tid = threadIdx.x, w = tid >> 6, lane = tid & 63, lo = lane & 15, hi = lane >> 4;
  const int qtA = ip, qtB = 15 - ip;
  const int qw0A = qtA * 128 + w * 16, qw0B = qtB * 128 + w * 16;
  const int ktA = 2 * qtA + 1;       // last K-tile index tile A needs (any wave)
  const int ktmax = 2 * qtB + 2;     // number of K-tiles tile B needs
  const bool trivial = flags[0] == 0;

  const unsigned short* Qb = Q + (size_t)bh * Sseq * HSn;
  const unsigned short* Kb = Kg + (size_t)bh * Sseq * HSn;
  const unsigned short* Vb = Vt + (size_t)bh * HSn * Sseq;

  // Q fragments (B-operand of swapped QK^T)
  s16x8 qfA[2], qfB[2];
#pragma unroll
  for (int kk = 0; kk < 2; ++kk) {
    qfA[kk] = *(const s16x8*)&Qb[(size_t)(qw0A + lo) * HSn + kk * 32 + hi * 8];
    qfB[kk] = *(const s16x8*)&Qb[(size_t)(qw0B + lo) * HSn + kk * 32 + hi * 8];
  }

  s16x8 ones;
#pragma unroll
  for (int j = 0; j < 8; ++j) ones[j] = (short)0x3F80; // bf16 1.0

  f32x4 oaccA[4] = {}, oaccB[4] = {};
  f32x4 laccA = {}, laccB = {};
  float mrunA = -3e38f, mrunB = -3e38f;

  // staging: waves 0-3 handle K (bit-permuted row order), waves 4-7 handle V
  const int shalf = tid >> 8, st_t = tid & 255;
  const int sr = st_t >> 2, sc = (st_t & 3) * 16;
  // logical K row for storage row sr: L = [s4 s3 s2 | s5 | s1 s0]
  const int srK = ((sr & 0x1C) << 1) | ((sr & 0x20) >> 3) | (sr & 3);

  // prologue: stage kt=0 into buffer 0
  s16x8 r0, r1;
  if (shalf == 0) {
    const unsigned short* gk = Kb + (size_t)srK * HSn + sc;
    r0 = *(const s16x8*)gk; r1 = *(const s16x8*)(gk + 8);
    *(s16x8*)&kb[0][sr * 72 + sc] = r0; *(s16x8*)&kb[0][sr * 72 + sc + 8] = r1;
  } else {
    const unsigned short* gv = Vb + (size_t)sr * Sseq + sc;
    r0 = *(const s16x8*)gv; r1 = *(const s16x8*)(gv + 8);
    *(s16x8*)&vb[0][sr * 72 + sc] = r0; *(s16x8*)&vb[0][sr * 72 + sc + 8] = r1;
  }
  __syncthreads();

  for (int kt = 0; kt < ktmax; ++kt) {
    const int cur = kt & 1, k0 = kt * 64;
    const bool pre = (kt + 1 < ktmax);
    if (pre) { // issue next-tile loads early; latency hides under compute
      const int k1 = k0 + 64;
      if (shalf == 0) {
        const unsigned short* gk = Kb + (size_t)(k1 + srK) * HSn + sc;
        r0 = *(const s16x8*)gk; r1 = *(const s16x8*)(gk + 8);
      } else {
        const unsigned short* gv = Vb + (size_t)sr * Sseq + k1 + sc;
        r0 = *(const s16x8*)gv; r1 = *(const s16x8*)(gv + 8);
      }
    }
    const unsigned short* kbc = kb[cur];
    const unsigned short* vbc = vb[cur];
    if (kt <= ktA)
      attn_unit16(kbc, vbc, qfA, oaccA, laccA, mrunA, ones,
                  k0, qw0A, lo, hi, b, pad, tmask, trivial);
    attn_unit16(kbc, vbc, qfB, oaccB, laccB, mrunB, ones,
                k0, qw0B, lo, hi, b, pad, tmask, trivial);
    if (pre) { // write-late into the other buffer
      const int nb = cur ^ 1;
      if (shalf == 0) {
        *(s16x8*)&kb[nb][sr * 72 + sc] = r0; *(s16x8*)&kb[nb][sr * 72 + sc + 8] = r1;
      } else {
        *(s16x8*)&vb[nb][sr * 72 + sc] = r0; *(s16x8*)&vb[nb][sr * 72 + sc + 8] = r1;
      }
    }
    __syncthreads();
  }

  // epilogue: per-wave scratch carved out of kb (all compute on kb finished above)
  unsigned short* scr = (unsigned short*)kb + (size_t)w * 1152;
  attn_epi16(oaccA, laccA[0], scr, O, b, hh, qw0A, lane, lo, hi);
  attn_epi16(oaccB, laccB[0], scr, O, b, hh, qw0B, lane, lo, hi);
}

extern "C" void kernel_launch(void* const* d_in, const int* in_sizes, int n_in,
                              void* d_out, int out_size, void* d_ws, size_t ws_size,
                              hipStream_t stream) {
  const float* x = (const float*)d_in[0];
  const float* y = (const float*)d_in[1];
  const int* pad = (const int*)d_in[2];
  const int* tmask = (const int*)d_in[3];
  const float* Wq = (const float*)d_in[4];
  const float* Wk = (const float*)d_in[5];
  const float* Wv = (const float*)d_in[6];
  const float* Wp = (const float*)d_in[7];
  const float* bp = (const float*)d_in[8];

  char* ws = (char*)d_ws;
  unsigned short* xbf = (unsigned short*)(ws + OFF_XBF);
  unsigned short* ybf = (unsigned short*)(ws + OFF_YBF);
  unsigned short* wqb = (unsigned short*)(ws + OFF_WQ);
  unsigned short* wkb = (unsigned short*)(ws + OFF_WK);
  unsigned short* wvb = (unsigned short*)(ws + OFF_WV);
  unsigned short* wpb = (unsigned short*)(ws + OFF_WP);
  unsigned short* qws = (unsigned short*)(ws + OFF_QWS);
  unsigned short* kws = (unsigned short*)(ws + OFF_KWS);
  unsigned short* vtw = (unsigned short*)(ws + OFF_VTWS);
  unsigned short* ows = (unsigned short*)(ws + OFF_OWS);
  int* flags = (int*)(ws + OFF_FLAG);

  hipMemsetAsync(flags, 0, 4, stream);
  cvt_all<<<12296, 256, 0, stream>>>(x, y, Wq, Wk, Wv, Wp, pad, tmask, ws, flags);

  qkv_gemm<<<dim3(64, 8, 2), 512, 0, stream>>>(xbf, ybf, wqb, wkb, wvb, qws, kws, vtw);

  attn_kernel<<<dim3(64, 8), 512, 0, stream>>>(qws, kws, vtw, ows, pad, tmask, flags);

  gemm_p<<<dim3(64, 8), 512, 0, stream>>>(ows, wpb, (float*)d_out, bp);
}